// Round 14
// baseline (417.589 us; speedup 1.0000x reference)
//
#include <hip/hip_runtime.h>
#include <math.h>

// Problem constants
#define B_   4096
#define N_   64
#define SS_  5
#define I_   7
#define H_   256
#define M1_  512
#define M2_  512
#define A_   81

typedef _Float16 f16;
typedef f16   f16x8 __attribute__((ext_vector_type(8)));
typedef float f32x4 __attribute__((ext_vector_type(4)));
typedef int   i32x4 __attribute__((ext_vector_type(4)));

__device__ __forceinline__ void fma4(float4& a, float s, const float4 w) {
  a.x = fmaf(s, w.x, a.x);
  a.y = fmaf(s, w.y, a.y);
  a.z = fmaf(s, w.z, a.z);
  a.w = fmaf(s, w.w, a.w);
}

__device__ __forceinline__ float4 relu4(float4 v) {
  v.x = fmaxf(v.x, 0.f); v.y = fmaxf(v.y, 0.f);
  v.z = fmaxf(v.z, 0.f); v.w = fmaxf(v.w, 0.f);
  return v;
}

__device__ __forceinline__ float sigm_(float x) {
  return __builtin_amdgcn_rcpf(1.f + __expf(-x));
}
__device__ __forceinline__ float tanh_(float x) {
  return 1.f - 2.f * __builtin_amdgcn_rcpf(__expf(2.f * x) + 1.f);
}

// ---------------------------------------------------------------------------
// Kernel 0: pack weights. One WAVE per packed column p (1024 waves).
// p = w*128 + ct*16 + l15 view; gate decomposition p = w*128 + g*32 + uu.
// Wq[kt][p][k32]  i8 linear (streamed tiles kt 4..7 read from here)
// Wql[kt][w][ct][l15][k32]  i8 image for kt 0..3 (byte-identical addressing,
//                           separate buffer staged to LDS)
// scd[p] = mx/127^2; bsum_p[p] = b_ih+b_hh; Wxk[p][8] f16 x-weights.
// ---------------------------------------------------------------------------
__global__ __launch_bounds__(1024) void pack_weights(
    const float* __restrict__ W_ih,
    const float* __restrict__ W_hh,
    const float* __restrict__ b_ih,
    const float* __restrict__ b_hh,
    signed char* __restrict__ Wq,
    signed char* __restrict__ Wql,
    f16* __restrict__ Wxk,
    float* __restrict__ bsum_p,
    float* __restrict__ scd) {
  const int gtid = blockIdx.x * 1024 + threadIdx.x;
  const int p    = gtid >> 6;           // one wave per column
  const int lane = gtid & 63;
  const int w = p >> 7, r = p & 127, g = r >> 5, uu = r & 31;
  const int row = g * H_ + w * 32 + uu;

  // lane owns k = lane*4 .. lane*4+3 (coalesced float4)
  const float4 v4 = *(const float4*)(W_hh + row * H_ + lane * 4);
  float mx = fmaxf(fmaxf(fabsf(v4.x), fabsf(v4.y)),
                   fmaxf(fabsf(v4.z), fabsf(v4.w)));
  #pragma unroll
  for (int off = 32; off; off >>= 1)
    mx = fmaxf(mx, __shfl_xor(mx, off));
  mx = fmaxf(mx, 1e-12f);
  const float is = 127.f / mx;

  int b0i = (int)rintf(v4.x * is), b1i = (int)rintf(v4.y * is);
  int b2i = (int)rintf(v4.z * is), b3i = (int)rintf(v4.w * is);
  b0i = max(-127, min(127, b0i)); b1i = max(-127, min(127, b1i));
  b2i = max(-127, min(127, b2i)); b3i = max(-127, min(127, b3i));
  const unsigned int packed = (b0i & 0xff) | ((b1i & 0xff) << 8) |
                              ((b2i & 0xff) << 16) | ((b3i & 0xff) << 24);
  const int kt  = lane >> 3;            // (lane*4)/32
  const int k32 = (lane & 7) * 4;       // k offset within the 32-wide tile
  *(unsigned int*)(Wq + kt * 32768 + p * 32 + k32) = packed;

  if (kt < 4)                           // LDS image, kt 0..3 (same addressing)
    *(unsigned int*)(Wql + kt * 32768 + p * 32 + k32) = packed;

  if (lane < 8)  Wxk[p * 8 + lane] = (lane < I_) ? (f16)W_ih[row * I_ + lane] : (f16)0.f;
  if (lane == 8)  bsum_p[p]  = b_ih[row] + b_hh[row];
  if (lane == 9)  scd[p]     = mx * (1.f / 16129.f);   // mx/127^2
}

// ---------------------------------------------------------------------------
// Kernel 1: distance + stable descending rank-sort + gather.
// xbuf: f16 [blk][rank(64)][bi(16)][8]; selfbuf: f32 [B][5].
// ---------------------------------------------------------------------------
__global__ void sort_gather(const float* __restrict__ state,
                            f16* __restrict__ xbuf,
                            float* __restrict__ selfbuf) {
  const int b = blockIdx.x;
  const int e = threadIdx.x;                 // 0..63, one wave
  const float* row = state + ((size_t)b * N_ + e) * 12;
  const float4* r4 = (const float4*)row;
  const float4 v0 = r4[0], v1 = r4[1], v2 = r4[2];
  float s[12];
  s[0]=v0.x; s[1]=v0.y; s[2]=v0.z;  s[3]=v0.w;
  s[4]=v1.x; s[5]=v1.y; s[6]=v1.z;  s[7]=v1.w;
  s[8]=v2.x; s[9]=v2.y; s[10]=v2.z; s[11]=v2.w;

  const float s5 = s[5], s6 = s[6];
  const float d = (s5 != 0.f && s6 != 0.f) ? sqrtf(s5 * s5 + s6 * s6) : INFINITY;

  __shared__ float dd[64];
  dd[e] = d;
  __syncthreads();

  int rank = 0;
  #pragma unroll
  for (int j = 0; j < 64; ++j) {
    const float dj = dd[j];
    rank += (dj > d || (dj == d && j < e)) ? 1 : 0;
  }

  f16* xo = xbuf + (((size_t)(b >> 4) * 64 + rank) * 16 + (b & 15)) * 8;
  #pragma unroll
  for (int f = 0; f < I_; ++f) xo[f] = (f16)s[SS_ + f];
  xo[7] = (f16)0.f;

  if (e == 0) {
    #pragma unroll
    for (int i = 0; i < SS_; ++i) selfbuf[b * SS_ + i] = s[i];
  }
}

// ---------------------------------------------------------------------------
// Kernel 2: i8 MFMA LSTM, LDS/stream-split weights. 256 blocks x 512
// threads (8 waves = 2/SIMD, 1 block/CU), 16 batches/block. Wave w owns
// packed cols [128w,128w+128): kt 0..3 of Wq staged ONCE in LDS (128 KB);
// kt 4..7 streamed from L2 each step (R9's proven sunk-load pattern; no
// register pinning — R5-R12 showed the allocator wins that fight).
// Per-step stream traffic halves vs R9. h quantized i8 with per-block
// per-step dynamic scale. x double-buffered in LDS (slab is [bi][8] padded,
// LINEAR 128-element indexing — R13's 7-stride remap bug fixed).
// LDS: Wl 131072 + Bx 16384 + hq 5120 + x 512 + wmax 32 = 153120 B.
// ---------------------------------------------------------------------------
__global__ __attribute__((amdgpu_flat_work_group_size(512, 512)))
void lstm_kernel(
    const f16* __restrict__ xbuf,      // [256][64][16][8]
    const signed char* __restrict__ Wq,// [8][1024][32] i8 (kt 4..7 used)
    const signed char* __restrict__ Wql,// [4][1024][32] i8 LDS image
    const f16* __restrict__ Wxk,       // [1024][8]
    const float* __restrict__ bsum_p,  // [1024]
    const float* __restrict__ scd,     // [1024]  mx/127^2
    float* __restrict__ hnbuf) {       // [B][256] fp32
  const int tid = threadIdx.x;
  const int l   = tid & 63;
  const int w   = tid >> 6;             // wave 0..7
  const int l15 = l & 15;
  const int lg  = l >> 4;               // 0..3
  const int b0  = blockIdx.x << 4;      // 16 batches per block

  extern __shared__ char smem[];
  signed char* Wl_s = (signed char*)smem;            // 131072 B
  f16*   Bx_s  = (f16*)(smem + 131072);              //  16384 B
  signed char* hq_s = (signed char*)(smem + 147456); //   5120 B [kt][b][40]
  f16*   x_s   = (f16*)(smem + 152576);              //    512 B [2][16][8]
  float* wmax_s = (float*)(smem + 153088);           //     32 B

  // --- one-time staging (coalesced linear copies) ---
  {
    const f16x8* sw = (const f16x8*)Wql;
    f16x8* dw = (f16x8*)Wl_s;
    for (int i = tid; i < 8192; i += 512) dw[i] = sw[i];
    const f16x8* sx = (const f16x8*)Wxk;
    f16x8* dx = (f16x8*)Bx_s;
    for (int i = tid; i < 1024; i += 512) dx[i] = sx[i];
    for (int i = tid; i < 1280; i += 512) ((int*)hq_s)[i] = 0;
    if (tid < 128) x_s[tid] = xbuf[(size_t)blockIdx.x * 8192 + tid]; // t=0 slab
  }

  // --- per-lane column constants (8 cols: p = w*128 + ct*16 + l15) ---
  float biasv[8], scv[8];
  #pragma unroll
  for (int ct = 0; ct < 8; ++ct) {
    const int p = w * 128 + ct * 16 + l15;
    biasv[ct] = bsum_p[p];
    scv[ct]   = scd[p];
  }

  const int qbase = w * 4096 + l15 * 32 + lg * 8;  // lane base within a kt slab
  const int hrd   = l15 * 40 + lg * 8;             // hq A-frag base (+kt*640)

  float c_[2][4];
  #pragma unroll
  for (int uh = 0; uh < 2; ++uh)
    #pragma unroll
    for (int q = 0; q < 4; ++q) c_[uh][q] = 0.f;

  float sh_prev = 1.f;

  __syncthreads();   // staging visible

  #pragma unroll 1
  for (int t = 0; t < 64; ++t) {
    // opaque zero defeats LICM on loop-invariant LDS reads (Wl, Bx):
    // without it the compiler hoists 96+ regs of LDS values and collapses.
    int z = 0;
    asm volatile("" : "+v"(z));

    // prefetch x for step t+1 (published into the other x buffer below)
    f16 xn = (f16)0.f;
    if (tid < 128) {
      const int tn = (t < 63) ? t + 1 : 63;
      xn = xbuf[(size_t)blockIdx.x * 8192 + tn * 128 + tid];
    }

    // x A-fragment: row=batch=l15, k=lg*8+j valid only for lg==0
    f16x8 ax = {(f16)0.f,(f16)0.f,(f16)0.f,(f16)0.f,
                (f16)0.f,(f16)0.f,(f16)0.f,(f16)0.f};
    if (lg == 0) ax = *(const f16x8*)&x_s[(t & 1) * 128 + l15 * 8 + z];

    i32x4 acc[8];
    #pragma unroll
    for (int ct = 0; ct < 8; ++ct) acc[ct] = (i32x4){0, 0, 0, 0};

    // kt 0..3: B from LDS
    #pragma unroll
    for (int kt = 0; kt < 4; ++kt) {
      const long Af = *(const long*)&hq_s[kt * 640 + hrd];
      #pragma unroll
      for (int ct = 0; ct < 8; ++ct) {
        const long Bv = *(const long*)(Wl_s + kt * 32768 + ct * 512 + qbase + z);
        acc[ct] = __builtin_amdgcn_mfma_i32_16x16x32_i8(Af, Bv, acc[ct], 0, 0, 0);
      }
    }
    // kt 4..7: B streamed from L2 (loads sink into the loop = streaming)
    #pragma unroll
    for (int kt = 4; kt < 8; ++kt) {
      const long Af = *(const long*)&hq_s[kt * 640 + hrd];
      #pragma unroll
      for (int ct = 0; ct < 8; ++ct) {
        const long Bv = *(const long*)(Wq + kt * 32768 + ct * 512 + qbase);
        acc[ct] = __builtin_amdgcn_mfma_i32_16x16x32_i8(Af, Bv, acc[ct], 0, 0, 0);
      }
    }

    // combine: facc = cvt(acc)*(mx*sh/127^2) + (bias + x@W_ih f16 MFMA)
    f32x4 facc[8];
    #pragma unroll
    for (int ct = 0; ct < 8; ++ct) {
      f32x4 accF = (f32x4){biasv[ct], biasv[ct], biasv[ct], biasv[ct]};
      const f16x8 Bv = *(const f16x8*)(Bx_s + (w * 128 + ct * 16 + l15) * 8 + z);
      accF = __builtin_amdgcn_mfma_f32_16x16x32_f16(ax, Bv, accF, 0, 0, 0);
      const float s2 = scv[ct] * sh_prev;
      #pragma unroll
      for (int e = 0; e < 4; ++e)
        facc[ct][e] = (float)acc[ct][e] * s2 + accF[e];
    }

    // gates + h, track block max|h|
    float hv[2][4];
    float mloc = 0.f;
    #pragma unroll
    for (int uh = 0; uh < 2; ++uh) {
      #pragma unroll
      for (int q = 0; q < 4; ++q) {
        const float gi = facc[0 + uh][q];
        const float gf = facc[2 + uh][q];
        const float gg = facc[4 + uh][q];
        const float go = facc[6 + uh][q];
        const float cn = sigm_(gf) * c_[uh][q] + sigm_(gi) * tanh_(gg);
        c_[uh][q] = cn;
        const float h = sigm_(go) * tanh_(cn);
        hv[uh][q] = h;
        mloc = fmaxf(mloc, fabsf(h));
      }
    }
    #pragma unroll
    for (int off = 32; off; off >>= 1)
      mloc = fmaxf(mloc, __shfl_xor(mloc, off));
    if (l == 0) wmax_s[w] = mloc;

    __syncthreads();   // hq/x reads done; wave maxes visible

    float sh = 1e-8f;
    #pragma unroll
    for (int j = 0; j < 8; ++j) sh = fmaxf(sh, wmax_s[j]);
    const float qs = 127.f / sh;

    // quantize h and publish; write hn at final step; publish next x
    #pragma unroll
    for (int uh = 0; uh < 2; ++uh) {
      const int wbq = w * 640 + uh * 16 + l15;
      const int u   = w * 32 + uh * 16 + l15;
      #pragma unroll
      for (int q = 0; q < 4; ++q) {
        const int b = lg * 4 + q;
        hq_s[wbq + b * 40] = (signed char)(int)rintf(hv[uh][q] * qs);
        if (t == 63) hnbuf[(size_t)(b0 + b) * H_ + u] = hv[uh][q];
      }
    }
    if (tid < 128) x_s[((t + 1) & 1) * 128 + tid] = xn;
    sh_prev = sh;
    __syncthreads();   // hq/x writes visible for next step
  }
}

// ---------------------------------------------------------------------------
// Kernel 3: fused MLP head. 512 blocks x 512 threads, 8 batches per block.
// LDS ~41 KB -> 2 blocks/CU = 4 waves/SIMD. unroll-8 k-loops for load ILP.
// ---------------------------------------------------------------------------
__global__ __launch_bounds__(512) void mlp_kernel(
    const float* __restrict__ selfb, const float* __restrict__ hnbuf,
    const float* __restrict__ W1, const float* __restrict__ b1,
    const float* __restrict__ W2, const float* __restrict__ b2,
    const float* __restrict__ Wv, const float* __restrict__ bv,
    float* __restrict__ out) {
  const int tid = threadIdx.x;
  const int b0  = blockIdx.x << 3;      // 8 batches per block
  const int tb  = tid >> 7;             // 0..3 (2 batches each)
  const int tn  = tid & 127;            // float4 column group (N=512)

  __shared__ float a0[8][264];
  __shared__ float a1[8][M1_];
  __shared__ float a2[8][M2_];

  for (int i = tid; i < 8 * SS_; i += 512)
    a0[i / SS_][i % SS_] = selfb[b0 * SS_ + i];
  for (int i = tid; i < 8 * H_; i += 512)
    a0[i >> 8][SS_ + (i & 255)] = hnbuf[((size_t)b0 << 8) + i];
  __syncthreads();

  float4 acc0, acc1;

  { // layer 1: K=261, N=512
    const float4* W14 = (const float4*)W1;
    const float4 bb = ((const float4*)b1)[tn];
    acc0 = bb; acc1 = bb;
    #pragma unroll 8
    for (int k = 0; k < SS_ + H_; ++k) {
      const float4 w0 = W14[k * 128 + tn];
      fma4(acc0, a0[tb * 2 + 0][k], w0);
      fma4(acc1, a0[tb * 2 + 1][k], w0);
    }
    *(float4*)&a1[tb * 2 + 0][tn << 2] = relu4(acc0);
    *(float4*)&a1[tb * 2 + 1][tn << 2] = relu4(acc1);
  }
  __syncthreads();

  { // layer 2: K=512, N=512
    const float4* W24 = (const float4*)W2;
    const float4 bb = ((const float4*)b2)[tn];
    acc0 = bb; acc1 = bb;
    #pragma unroll 8
    for (int k = 0; k < M1_; ++k) {
      const float4 w0 = W24[k * 128 + tn];
      fma4(acc0, a1[tb * 2 + 0][k], w0);
      fma4(acc1, a1[tb * 2 + 1][k], w0);
    }
    *(float4*)&a2[tb * 2 + 0][tn << 2] = relu4(acc0);
    *(float4*)&a2[tb * 2 + 1][tn << 2] = relu4(acc1);
  }
  __syncthreads();

  // layer 3: K=512, N=81
  for (int idx = tid; idx < 8 * A_; idx += 512) {
    const int bi = idx / A_;
    const int n  = idx - bi * A_;
    float sum = bv[n];
    #pragma unroll 8
    for (int k = 0; k < M2_; ++k)
      sum = fmaf(a2[bi][k], Wv[k * A_ + n], sum);
    out[(size_t)(b0 + bi) * A_ + n] = sum;
  }
}

// ---------------------------------------------------------------------------
extern "C" void kernel_launch(void* const* d_in, const int* in_sizes, int n_in,
                              void* d_out, int out_size, void* d_ws, size_t ws_size,
                              hipStream_t stream) {
  const float* state = (const float*)d_in[0];
  const float* W_ih  = (const float*)d_in[1];
  const float* W_hh  = (const float*)d_in[2];
  const float* b_ih  = (const float*)d_in[3];
  const float* b_hh  = (const float*)d_in[4];
  const float* W1    = (const float*)d_in[5];
  const float* b1    = (const float*)d_in[6];
  const float* W2    = (const float*)d_in[7];
  const float* b2    = (const float*)d_in[8];
  const float* Wv    = (const float*)d_in[9];
  const float* bv    = (const float*)d_in[10];
  float* out = (float*)d_out;

  // workspace layout (bytes, 16B-aligned); total ~8.9 MB
  char* ws = (char*)d_ws;
  signed char* Wq  = (signed char*)(ws);          // 8*1024*32 i8 = 262144 B
  signed char* Wql = (signed char*)(ws + 262144); // 4*32768      = 131072 B
  f16*   Wxk     = (f16*)(ws + 393216);           // 1024*8 f16   = 16384 B
  float* bsum_p  = (float*)(ws + 409600);         // 1024 f32     = 4096 B
  float* scd     = (float*)(ws + 413696);         // 1024 f32     = 4096 B
  f16*   xbuf    = (f16*)(ws + 417792);           // 256*64*16*8  = 4194304 B
  float* selfb   = (float*)(ws + 4612096);        // 4096*5 f32   = 81920 B
  float* hnbuf   = (float*)(ws + 4694016);        // 4096*256 f32 = 4194304 B

  pack_weights<<<dim3(64), dim3(1024), 0, stream>>>(W_ih, W_hh, b_ih, b_hh,
                                                    Wq, Wql, Wxk, bsum_p, scd);
  sort_gather<<<dim3(B_), dim3(64), 0, stream>>>(state, xbuf, selfb);
  lstm_kernel<<<dim3(B_ / 16), dim3(512), 153120, stream>>>(xbuf, Wq, Wql, Wxk,
                                                            bsum_p, scd, hnbuf);
  mlp_kernel<<<dim3(B_ / 8), dim3(512), 0, stream>>>(selfb, hnbuf, W1, b1,
                                                     W2, b2, Wv, bv, out);
}

// Round 15
// 378.374 us; speedup vs baseline: 1.1036x; 1.1036x over previous
//
#include <hip/hip_runtime.h>
#include <math.h>

// Problem constants
#define B_   4096
#define N_   64
#define SS_  5
#define I_   7
#define H_   256
#define M1_  512
#define M2_  512
#define A_   81

typedef _Float16 f16;
typedef f16   f16x8 __attribute__((ext_vector_type(8)));
typedef float f32x4 __attribute__((ext_vector_type(4)));
typedef int   i32x4 __attribute__((ext_vector_type(4)));

__device__ __forceinline__ void fma4(float4& a, float s, const float4 w) {
  a.x = fmaf(s, w.x, a.x);
  a.y = fmaf(s, w.y, a.y);
  a.z = fmaf(s, w.z, a.z);
  a.w = fmaf(s, w.w, a.w);
}

__device__ __forceinline__ float4 relu4(float4 v) {
  v.x = fmaxf(v.x, 0.f); v.y = fmaxf(v.y, 0.f);
  v.z = fmaxf(v.z, 0.f); v.w = fmaxf(v.w, 0.f);
  return v;
}

__device__ __forceinline__ float sigm_(float x) {
  return __builtin_amdgcn_rcpf(1.f + __expf(-x));
}
__device__ __forceinline__ float tanh_(float x) {
  return 1.f - 2.f * __builtin_amdgcn_rcpf(__expf(2.f * x) + 1.f);
}

// ---------------------------------------------------------------------------
// Kernel 0: pack weights. One WAVE per packed column p (1024 waves).
// 16-wave column order: p = w16*64 + g*16 + uu  (wave w16 owns 64 cols =
// 4 gates x 16 units u = w16*16 + uu); original row = g*256 + w16*16 + uu.
// Wq[kt][p][32]  i8 k-major (streamed kt 4..7; coalesced 512B per (w,g))
// Wql[kt][w16][g][lane*8+j] i8 TRUE lane-contiguous (conflict-free LDS b64):
//    lane l = lg*16+l15 holds col l15, k = kt*32+lg*8+j.
// scd[p] = mx/127^2; bsum_p[p] = b_ih+b_hh; Wxk[p][8] f16 x-weights.
// ---------------------------------------------------------------------------
__global__ __launch_bounds__(1024) void pack_weights(
    const float* __restrict__ W_ih,
    const float* __restrict__ W_hh,
    const float* __restrict__ b_ih,
    const float* __restrict__ b_hh,
    signed char* __restrict__ Wq,
    signed char* __restrict__ Wql,
    f16* __restrict__ Wxk,
    float* __restrict__ bsum_p,
    float* __restrict__ scd) {
  const int gtid = blockIdx.x * 1024 + threadIdx.x;
  const int p    = gtid >> 6;           // one wave per column
  const int lane = gtid & 63;
  const int w16 = p >> 6, r = p & 63, g = r >> 4, uu = r & 15;
  const int row = g * H_ + w16 * 16 + uu;

  // lane owns k = lane*4 .. lane*4+3 (coalesced float4)
  const float4 v4 = *(const float4*)(W_hh + row * H_ + lane * 4);
  float mx = fmaxf(fmaxf(fabsf(v4.x), fabsf(v4.y)),
                   fmaxf(fabsf(v4.z), fabsf(v4.w)));
  #pragma unroll
  for (int off = 32; off; off >>= 1)
    mx = fmaxf(mx, __shfl_xor(mx, off));
  mx = fmaxf(mx, 1e-12f);
  const float is = 127.f / mx;

  int b0i = (int)rintf(v4.x * is), b1i = (int)rintf(v4.y * is);
  int b2i = (int)rintf(v4.z * is), b3i = (int)rintf(v4.w * is);
  b0i = max(-127, min(127, b0i)); b1i = max(-127, min(127, b1i));
  b2i = max(-127, min(127, b2i)); b3i = max(-127, min(127, b3i));
  const unsigned int packed = (b0i & 0xff) | ((b1i & 0xff) << 8) |
                              ((b2i & 0xff) << 16) | ((b3i & 0xff) << 24);
  const int kt  = lane >> 3;            // (lane*4)/32
  const int k32 = (lane & 7) * 4;       // k offset within the 32-wide tile
  *(unsigned int*)(Wq + kt * 32768 + p * 32 + k32) = packed;

  if (kt < 4) {                         // lane-contiguous LDS image, kt 0..3
    const int lg = (lane & 7) >> 1;     // k32 >> 3
    const int j0 = (lane & 1) * 4;      // k32 & 7
    *(unsigned int*)(Wql + kt * 32768 + w16 * 2048 + g * 512 +
                     (lg * 16 + uu) * 8 + j0) = packed;
  }

  if (lane < 8)  Wxk[p * 8 + lane] = (lane < I_) ? (f16)W_ih[row * I_ + lane] : (f16)0.f;
  if (lane == 8)  bsum_p[p]  = b_ih[row] + b_hh[row];
  if (lane == 9)  scd[p]     = mx * (1.f / 16129.f);   // mx/127^2
}

// ---------------------------------------------------------------------------
// Kernel 1: distance + stable descending rank-sort + gather.
// xbuf: f16 [blk][rank(64)][bi(16)][8]; selfbuf: f32 [B][5].
// ---------------------------------------------------------------------------
__global__ void sort_gather(const float* __restrict__ state,
                            f16* __restrict__ xbuf,
                            float* __restrict__ selfbuf) {
  const int b = blockIdx.x;
  const int e = threadIdx.x;                 // 0..63, one wave
  const float* row = state + ((size_t)b * N_ + e) * 12;
  const float4* r4 = (const float4*)row;
  const float4 v0 = r4[0], v1 = r4[1], v2 = r4[2];
  float s[12];
  s[0]=v0.x; s[1]=v0.y; s[2]=v0.z;  s[3]=v0.w;
  s[4]=v1.x; s[5]=v1.y; s[6]=v1.z;  s[7]=v1.w;
  s[8]=v2.x; s[9]=v2.y; s[10]=v2.z; s[11]=v2.w;

  const float s5 = s[5], s6 = s[6];
  const float d = (s5 != 0.f && s6 != 0.f) ? sqrtf(s5 * s5 + s6 * s6) : INFINITY;

  __shared__ float dd[64];
  dd[e] = d;
  __syncthreads();

  int rank = 0;
  #pragma unroll
  for (int j = 0; j < 64; ++j) {
    const float dj = dd[j];
    rank += (dj > d || (dj == d && j < e)) ? 1 : 0;
  }

  f16* xo = xbuf + (((size_t)(b >> 4) * 64 + rank) * 16 + (b & 15)) * 8;
  #pragma unroll
  for (int f = 0; f < I_; ++f) xo[f] = (f16)s[SS_ + f];
  xo[7] = (f16)0.f;

  if (e == 0) {
    #pragma unroll
    for (int i = 0; i < SS_; ++i) selfbuf[b * SS_ + i] = s[i];
  }
}

// ---------------------------------------------------------------------------
// Kernel 2: i8 MFMA LSTM, 16 waves (4/SIMD) + LDS/stream-split weights.
// 256 blocks x 1024 threads, 16 batches/block. Wave w owns 64 packed cols
// (4 gates x units w*16+l15): kt 0..3 in LDS (lane-contiguous, conflict-
// free); kt 4..7 streamed from L2 (coalesced 512B reads). Per-wave work
// halves vs R14; 4 waves/SIMD overlap L2 latency, LDS, trans & VALU.
// h quantized i8 with per-block per-step dynamic scale.
// LDS: Wl 131072 + Bx 16384 + hq 5120 + x 512 + wmax 64 = 153152 B.
// ---------------------------------------------------------------------------
__global__ __attribute__((amdgpu_flat_work_group_size(1024, 1024)))
void lstm_kernel(
    const f16* __restrict__ xbuf,      // [256][64][16][8]
    const signed char* __restrict__ Wq,// [8][1024][32] i8 (kt 4..7 used)
    const signed char* __restrict__ Wql,// [4][16][4][512] lane-contiguous
    const f16* __restrict__ Wxk,       // [1024][8]
    const float* __restrict__ bsum_p,  // [1024]
    const float* __restrict__ scd,     // [1024]  mx/127^2
    float* __restrict__ hnbuf) {       // [B][256] fp32
  const int tid = threadIdx.x;
  const int l   = tid & 63;
  const int w   = tid >> 6;             // wave 0..15
  const int l15 = l & 15;
  const int lg  = l >> 4;               // 0..3
  const int b0  = blockIdx.x << 4;      // 16 batches per block

  extern __shared__ char smem[];
  signed char* Wl_s = (signed char*)smem;            // 131072 B
  f16*   Bx_s  = (f16*)(smem + 131072);              //  16384 B
  signed char* hq_s = (signed char*)(smem + 147456); //   5120 B [kt][b][40]
  f16*   x_s   = (f16*)(smem + 152576);              //    512 B [2][16][8]
  float* wmax_s = (float*)(smem + 153088);           //     64 B

  // --- one-time staging (coalesced linear copies) ---
  {
    const f16x8* sw = (const f16x8*)Wql;
    f16x8* dw = (f16x8*)Wl_s;
    for (int i = tid; i < 8192; i += 1024) dw[i] = sw[i];
    const f16x8* sx = (const f16x8*)Wxk;
    f16x8* dx = (f16x8*)Bx_s;
    for (int i = tid; i < 1024; i += 1024) dx[i] = sx[i];
    for (int i = tid; i < 1280; i += 1024) ((int*)hq_s)[i] = 0;
    if (tid < 128) x_s[tid] = xbuf[(size_t)blockIdx.x * 8192 + tid]; // t=0 slab
  }

  // --- per-lane column constants (4 cols: p = w*64 + g*16 + l15) ---
  float biasv[4], scv[4];
  #pragma unroll
  for (int g = 0; g < 4; ++g) {
    const int p = w * 64 + g * 16 + l15;
    biasv[g] = bsum_p[p];
    scv[g]   = scd[p];
  }

  const int sbase = w * 2048 + l15 * 32 + lg * 8;  // streamed lane base (+g*512)
  const int lbase = w * 2048 + l * 8;              // LDS lane base (+g*512)
  const int hrd   = l15 * 40 + lg * 8;             // hq A-frag base (+kt*640)

  float c_[4] = {0.f, 0.f, 0.f, 0.f};
  float sh_prev = 1.f;

  __syncthreads();   // staging visible

  #pragma unroll 1
  for (int t = 0; t < 64; ++t) {
    // opaque zero defeats LICM on loop-invariant LDS reads
    int z = 0;
    asm volatile("" : "+v"(z));

    // prefetch x for step t+1 (published into the other x buffer below)
    f16 xn = (f16)0.f;
    if (tid < 128) {
      const int tn = (t < 63) ? t + 1 : 63;
      xn = xbuf[(size_t)blockIdx.x * 8192 + tn * 128 + tid];
    }

    // x A-fragment: row=batch=l15, k=lg*8+j valid only for lg==0
    f16x8 ax = {(f16)0.f,(f16)0.f,(f16)0.f,(f16)0.f,
                (f16)0.f,(f16)0.f,(f16)0.f,(f16)0.f};
    if (lg == 0) ax = *(const f16x8*)&x_s[(t & 1) * 128 + l15 * 8 + z];

    i32x4 acc[4];
    #pragma unroll
    for (int g = 0; g < 4; ++g) acc[g] = (i32x4){0, 0, 0, 0};

    // kt 0..3: B from LDS (lane-contiguous -> conflict-free b64)
    #pragma unroll
    for (int kt = 0; kt < 4; ++kt) {
      const long Af = *(const long*)&hq_s[kt * 640 + hrd];
      #pragma unroll
      for (int g = 0; g < 4; ++g) {
        const long Bv = *(const long*)(Wl_s + kt * 32768 + g * 512 + lbase + z);
        acc[g] = __builtin_amdgcn_mfma_i32_16x16x32_i8(Af, Bv, acc[g], 0, 0, 0);
      }
    }
    // kt 4..7: B streamed from L2 (coalesced 512B per (wave,g) read)
    #pragma unroll
    for (int kt = 4; kt < 8; ++kt) {
      const long Af = *(const long*)&hq_s[kt * 640 + hrd];
      #pragma unroll
      for (int g = 0; g < 4; ++g) {
        const long Bv = *(const long*)(Wq + kt * 32768 + g * 512 + sbase);
        acc[g] = __builtin_amdgcn_mfma_i32_16x16x32_i8(Af, Bv, acc[g], 0, 0, 0);
      }
    }

    // combine: facc = cvt(acc)*(mx*sh/127^2) + (bias + x@W_ih f16 MFMA)
    f32x4 facc[4];
    #pragma unroll
    for (int g = 0; g < 4; ++g) {
      f32x4 accF = (f32x4){biasv[g], biasv[g], biasv[g], biasv[g]};
      const f16x8 Bv = *(const f16x8*)(Bx_s + (w * 64 + g * 16 + l15) * 8 + z);
      accF = __builtin_amdgcn_mfma_f32_16x16x32_f16(ax, Bv, accF, 0, 0, 0);
      const float s2 = scv[g] * sh_prev;
      #pragma unroll
      for (int e = 0; e < 4; ++e)
        facc[g][e] = (float)acc[g][e] * s2 + accF[e];
    }

    // gates + h for unit u = w*16+l15, batches lg*4+q; track block max|h|
    float hv[4];
    float mloc = 0.f;
    #pragma unroll
    for (int q = 0; q < 4; ++q) {
      const float gi = facc[0][q];
      const float gf = facc[1][q];
      const float gg = facc[2][q];
      const float go = facc[3][q];
      const float cn = sigm_(gf) * c_[q] + sigm_(gi) * tanh_(gg);
      c_[q] = cn;
      const float h = sigm_(go) * tanh_(cn);
      hv[q] = h;
      mloc = fmaxf(mloc, fabsf(h));
    }
    #pragma unroll
    for (int off = 32; off; off >>= 1)
      mloc = fmaxf(mloc, __shfl_xor(mloc, off));
    if (l == 0) wmax_s[w] = mloc;

    __syncthreads();   // hq/x reads done; wave maxes visible

    float sh = 1e-8f;
    #pragma unroll
    for (int j = 0; j < 16; ++j) sh = fmaxf(sh, wmax_s[j]);
    const float qs = 127.f / sh;

    // quantize h and publish; write hn at final step; publish next x
    {
      const int u   = w * 16 + l15;
      const int wbq = (u >> 5) * 640 + (u & 31);
      #pragma unroll
      for (int q = 0; q < 4; ++q) {
        const int b = lg * 4 + q;
        hq_s[wbq + b * 40] = (signed char)(int)rintf(hv[q] * qs);
        if (t == 63) hnbuf[(size_t)(b0 + b) * H_ + u] = hv[q];
      }
    }
    if (tid < 128) x_s[((t + 1) & 1) * 128 + tid] = xn;
    sh_prev = sh;
    __syncthreads();   // hq/x writes visible for next step
  }
}

// ---------------------------------------------------------------------------
// Kernel 3: fused MLP head. 512 blocks x 512 threads, 8 batches per block.
// LDS ~41 KB -> 2 blocks/CU = 4 waves/SIMD. unroll-8 k-loops for load ILP.
// ---------------------------------------------------------------------------
__global__ __launch_bounds__(512) void mlp_kernel(
    const float* __restrict__ selfb, const float* __restrict__ hnbuf,
    const float* __restrict__ W1, const float* __restrict__ b1,
    const float* __restrict__ W2, const float* __restrict__ b2,
    const float* __restrict__ Wv, const float* __restrict__ bv,
    float* __restrict__ out) {
  const int tid = threadIdx.x;
  const int b0  = blockIdx.x << 3;      // 8 batches per block
  const int tb  = tid >> 7;             // 0..3 (2 batches each)
  const int tn  = tid & 127;            // float4 column group (N=512)

  __shared__ float a0[8][264];
  __shared__ float a1[8][M1_];
  __shared__ float a2[8][M2_];

  for (int i = tid; i < 8 * SS_; i += 512)
    a0[i / SS_][i % SS_] = selfb[b0 * SS_ + i];
  for (int i = tid; i < 8 * H_; i += 512)
    a0[i >> 8][SS_ + (i & 255)] = hnbuf[((size_t)b0 << 8) + i];
  __syncthreads();

  float4 acc0, acc1;

  { // layer 1: K=261, N=512
    const float4* W14 = (const float4*)W1;
    const float4 bb = ((const float4*)b1)[tn];
    acc0 = bb; acc1 = bb;
    #pragma unroll 8
    for (int k = 0; k < SS_ + H_; ++k) {
      const float4 w0 = W14[k * 128 + tn];
      fma4(acc0, a0[tb * 2 + 0][k], w0);
      fma4(acc1, a0[tb * 2 + 1][k], w0);
    }
    *(float4*)&a1[tb * 2 + 0][tn << 2] = relu4(acc0);
    *(float4*)&a1[tb * 2 + 1][tn << 2] = relu4(acc1);
  }
  __syncthreads();

  { // layer 2: K=512, N=512
    const float4* W24 = (const float4*)W2;
    const float4 bb = ((const float4*)b2)[tn];
    acc0 = bb; acc1 = bb;
    #pragma unroll 8
    for (int k = 0; k < M1_; ++k) {
      const float4 w0 = W24[k * 128 + tn];
      fma4(acc0, a1[tb * 2 + 0][k], w0);
      fma4(acc1, a1[tb * 2 + 1][k], w0);
    }
    *(float4*)&a2[tb * 2 + 0][tn << 2] = relu4(acc0);
    *(float4*)&a2[tb * 2 + 1][tn << 2] = relu4(acc1);
  }
  __syncthreads();

  // layer 3: K=512, N=81
  for (int idx = tid; idx < 8 * A_; idx += 512) {
    const int bi = idx / A_;
    const int n  = idx - bi * A_;
    float sum = bv[n];
    #pragma unroll 8
    for (int k = 0; k < M2_; ++k)
      sum = fmaf(a2[bi][k], Wv[k * A_ + n], sum);
    out[(size_t)(b0 + bi) * A_ + n] = sum;
  }
}

// ---------------------------------------------------------------------------
extern "C" void kernel_launch(void* const* d_in, const int* in_sizes, int n_in,
                              void* d_out, int out_size, void* d_ws, size_t ws_size,
                              hipStream_t stream) {
  const float* state = (const float*)d_in[0];
  const float* W_ih  = (const float*)d_in[1];
  const float* W_hh  = (const float*)d_in[2];
  const float* b_ih  = (const float*)d_in[3];
  const float* b_hh  = (const float*)d_in[4];
  const float* W1    = (const float*)d_in[5];
  const float* b1    = (const float*)d_in[6];
  const float* W2    = (const float*)d_in[7];
  const float* b2    = (const float*)d_in[8];
  const float* Wv    = (const float*)d_in[9];
  const float* bv    = (const float*)d_in[10];
  float* out = (float*)d_out;

  // workspace layout (bytes, 16B-aligned); total ~8.9 MB
  char* ws = (char*)d_ws;
  signed char* Wq  = (signed char*)(ws);          // 8*1024*32 i8 = 262144 B
  signed char* Wql = (signed char*)(ws + 262144); // 4*32768      = 131072 B
  f16*   Wxk     = (f16*)(ws + 393216);           // 1024*8 f16   = 16384 B
  float* bsum_p  = (float*)(ws + 409600);         // 1024 f32     = 4096 B
  float* scd     = (float*)(ws + 413696);         // 1024 f32     = 4096 B
  f16*   xbuf    = (f16*)(ws + 417792);           // 256*64*16*8  = 4194304 B
  float* selfb   = (float*)(ws + 4612096);        // 4096*5 f32   = 81920 B
  float* hnbuf   = (float*)(ws + 4694016);        // 4096*256 f32 = 4194304 B

  pack_weights<<<dim3(64), dim3(1024), 0, stream>>>(W_ih, W_hh, b_ih, b_hh,
                                                    Wq, Wql, Wxk, bsum_p, scd);
  sort_gather<<<dim3(B_), dim3(64), 0, stream>>>(state, xbuf, selfb);
  lstm_kernel<<<dim3(B_ / 16), dim3(1024), 153152, stream>>>(xbuf, Wq, Wql, Wxk,
                                                             bsum_p, scd, hnbuf);
  mlp_kernel<<<dim3(B_ / 8), dim3(512), 0, stream>>>(selfb, hnbuf, W1, b1,
                                                     W2, b2, Wv, bv, out);
}

// Round 16
// 356.547 us; speedup vs baseline: 1.1712x; 1.0612x over previous
//
#include <hip/hip_runtime.h>
#include <math.h>

// Problem constants
#define B_   4096
#define N_   64
#define SS_  5
#define I_   7
#define H_   256
#define M1_  512
#define M2_  512
#define A_   81

typedef _Float16 f16;
typedef f16   f16x8 __attribute__((ext_vector_type(8)));
typedef float f32x4 __attribute__((ext_vector_type(4)));
typedef int   i32x4 __attribute__((ext_vector_type(4)));

__device__ __forceinline__ void fma4(float4& a, float s, const float4 w) {
  a.x = fmaf(s, w.x, a.x);
  a.y = fmaf(s, w.y, a.y);
  a.z = fmaf(s, w.z, a.z);
  a.w = fmaf(s, w.w, a.w);
}

__device__ __forceinline__ float4 relu4(float4 v) {
  v.x = fmaxf(v.x, 0.f); v.y = fmaxf(v.y, 0.f);
  v.z = fmaxf(v.z, 0.f); v.w = fmaxf(v.w, 0.f);
  return v;
}

__device__ __forceinline__ float sigm_(float x) {
  return __builtin_amdgcn_rcpf(1.f + __expf(-x));
}
__device__ __forceinline__ float tanh_(float x) {
  return 1.f - 2.f * __builtin_amdgcn_rcpf(__expf(2.f * x) + 1.f);
}

// ---------------------------------------------------------------------------
// Kernel 0: pack weights for K=64 i8 MFMA. One WAVE per packed column p.
// p = w16*64 + g*16 + uu (wave w16 owns 64 cols); original row = g*256+w16*16+uu.
// Wq2[kt2][p][64]  i8 k-major, kt2 in [0,4) (streamed kt2 2,3: lane reads
//                  16B at p*64 + lg*16 -> k-mapping k = kt2*64 + lg*16 + j,
//                  SAME mapping used for A, so any permutation cancels)
// Wql2[kt2][w16][g][lane*16] kt2 0,1: lane-contiguous LDS image
//                  (lane l = lg*16+l15 holds col l15, kk = lg*16 + j)
// scd[p] = mx/127^2 (fixed h scale qs=127); bsum_p; Wxk[p][8] f16.
// ---------------------------------------------------------------------------
__global__ __launch_bounds__(1024) void pack_weights(
    const float* __restrict__ W_ih,
    const float* __restrict__ W_hh,
    const float* __restrict__ b_ih,
    const float* __restrict__ b_hh,
    signed char* __restrict__ Wq2,
    signed char* __restrict__ Wql2,
    f16* __restrict__ Wxk,
    float* __restrict__ bsum_p,
    float* __restrict__ scd) {
  const int gtid = blockIdx.x * 1024 + threadIdx.x;
  const int p    = gtid >> 6;           // one wave per column
  const int lane = gtid & 63;
  const int w16 = p >> 6, r = p & 63, g = r >> 4, uu = r & 15;
  const int row = g * H_ + w16 * 16 + uu;

  // lane owns k = lane*4 .. lane*4+3 (coalesced float4)
  const float4 v4 = *(const float4*)(W_hh + row * H_ + lane * 4);
  float mx = fmaxf(fmaxf(fabsf(v4.x), fabsf(v4.y)),
                   fmaxf(fabsf(v4.z), fabsf(v4.w)));
  #pragma unroll
  for (int off = 32; off; off >>= 1)
    mx = fmaxf(mx, __shfl_xor(mx, off));
  mx = fmaxf(mx, 1e-12f);
  const float is = 127.f / mx;

  int b0i = (int)rintf(v4.x * is), b1i = (int)rintf(v4.y * is);
  int b2i = (int)rintf(v4.z * is), b3i = (int)rintf(v4.w * is);
  b0i = max(-127, min(127, b0i)); b1i = max(-127, min(127, b1i));
  b2i = max(-127, min(127, b2i)); b3i = max(-127, min(127, b3i));
  const unsigned int packed = (b0i & 0xff) | ((b1i & 0xff) << 8) |
                              ((b2i & 0xff) << 16) | ((b3i & 0xff) << 24);
  const int k    = lane * 4;
  const int kt2  = k >> 6;              // 64-wide K tile
  const int kk   = k & 63;
  *(unsigned int*)(Wq2 + kt2 * 65536 + p * 64 + kk) = packed;

  if (kt2 < 2) {                        // lane-contiguous LDS image
    const int lgk = kk >> 4;            // which 16-k group
    const int jq  = kk & 15;            // 4-aligned within group
    *(unsigned int*)(Wql2 + ((kt2 * 16 + w16) * 4 + g) * 1024 +
                     lgk * 256 + uu * 16 + jq) = packed;
  }

  if (lane < 8)  Wxk[p * 8 + lane] = (lane < I_) ? (f16)W_ih[row * I_ + lane] : (f16)0.f;
  if (lane == 8)  bsum_p[p]  = b_ih[row] + b_hh[row];
  if (lane == 9)  scd[p]     = mx * (1.f / 16129.f);   // mx/127^2
}

// ---------------------------------------------------------------------------
// Kernel 1: distance + stable descending rank-sort + gather.
// xbuf: f16 [blk][rank(64)][bi(16)][8]; selfbuf: f32 [B][5].
// ---------------------------------------------------------------------------
__global__ void sort_gather(const float* __restrict__ state,
                            f16* __restrict__ xbuf,
                            float* __restrict__ selfbuf) {
  const int b = blockIdx.x;
  const int e = threadIdx.x;                 // 0..63, one wave
  const float* row = state + ((size_t)b * N_ + e) * 12;
  const float4* r4 = (const float4*)row;
  const float4 v0 = r4[0], v1 = r4[1], v2 = r4[2];
  float s[12];
  s[0]=v0.x; s[1]=v0.y; s[2]=v0.z;  s[3]=v0.w;
  s[4]=v1.x; s[5]=v1.y; s[6]=v1.z;  s[7]=v1.w;
  s[8]=v2.x; s[9]=v2.y; s[10]=v2.z; s[11]=v2.w;

  const float s5 = s[5], s6 = s[6];
  const float d = (s5 != 0.f && s6 != 0.f) ? sqrtf(s5 * s5 + s6 * s6) : INFINITY;

  __shared__ float dd[64];
  dd[e] = d;
  __syncthreads();

  int rank = 0;
  #pragma unroll
  for (int j = 0; j < 64; ++j) {
    const float dj = dd[j];
    rank += (dj > d || (dj == d && j < e)) ? 1 : 0;
  }

  f16* xo = xbuf + (((size_t)(b >> 4) * 64 + rank) * 16 + (b & 15)) * 8;
  #pragma unroll
  for (int f = 0; f < I_; ++f) xo[f] = (f16)s[SS_ + f];
  xo[7] = (f16)0.f;

  if (e == 0) {
    #pragma unroll
    for (int i = 0; i < SS_; ++i) selfbuf[b * SS_ + i] = s[i];
  }
}

// ---------------------------------------------------------------------------
// Kernel 2: i8 K=64 MFMA LSTM. 256 blocks x 1024 threads (16 waves,
// 4/SIMD), 16 batches/block. Wave w owns 64 packed cols (4 gates x units
// w*16+l15): kt2 0,1 in LDS (lane-contiguous, conflict-free b128); kt2 2,3
// streamed from L2 (coalesced). 16 i8 MFMA + 4 f16 MFMA per wave-step
// (half R15's instruction count). hq double-buffered -> ONE barrier/step.
// Fixed h scale qs=127 (|h|<1 always) -> no cross-wave reduce.
// LDS: Wl 131072 + Bx 16384 + hq 2x4096 + x 512 = 156160 B.
// ---------------------------------------------------------------------------
__global__ __attribute__((amdgpu_flat_work_group_size(1024, 1024)))
void lstm_kernel(
    const f16* __restrict__ xbuf,       // [256][64][16][8]
    const signed char* __restrict__ Wq2,// [4][1024][64] i8 (kt2 2,3 used)
    const signed char* __restrict__ Wql2,// [2][16][4][1024] lane-contiguous
    const f16* __restrict__ Wxk,        // [1024][8]
    const float* __restrict__ bsum_p,   // [1024]
    const float* __restrict__ scd,      // [1024]  mx/127^2
    float* __restrict__ hnbuf) {        // [B][256] fp32
  const int tid = threadIdx.x;
  const int l   = tid & 63;
  const int w   = tid >> 6;             // wave 0..15
  const int l15 = l & 15;
  const int lg  = l >> 4;               // 0..3
  const int b0  = blockIdx.x << 4;      // 16 batches per block

  extern __shared__ char smem[];
  signed char* Wl_s = (signed char*)smem;            // 131072 B
  f16*   Bx_s  = (f16*)(smem + 131072);              //  16384 B
  signed char* hq_s = (signed char*)(smem + 147456); //   8192 B [2][4][16][64]
  f16*   x_s   = (f16*)(smem + 155648);              //    512 B [2][16][8]

  // --- one-time staging (coalesced linear copies) ---
  {
    const f16x8* sw = (const f16x8*)Wql2;
    f16x8* dw = (f16x8*)Wl_s;
    for (int i = tid; i < 8192; i += 1024) dw[i] = sw[i];
    const f16x8* sx = (const f16x8*)Wxk;
    f16x8* dx = (f16x8*)Bx_s;
    for (int i = tid; i < 1024; i += 1024) dx[i] = sx[i];
    for (int i = tid; i < 2048; i += 1024) ((int*)hq_s)[i] = 0;
    if (tid < 128) x_s[tid] = xbuf[(size_t)blockIdx.x * 8192 + tid]; // t=0 slab
  }

  // --- per-lane column constants (4 cols: p = w*64 + g*16 + l15) ---
  float biasv[4], scv[4];
  #pragma unroll
  for (int g = 0; g < 4; ++g) {
    const int p = w * 64 + g * 16 + l15;
    biasv[g] = bsum_p[p];
    scv[g]   = scd[p];
  }

  const int WLB = w * 4096 + l * 16;           // LDS W base (+kt2*65536+g*1024)
  const int SB  = w * 4096 + l15 * 64 + lg * 16; // stream base (+kt2*65536+g*1024)
  const int HR  = l15 * 64 + lg * 16;          // hq A-frag base (+kt2*1024)
  const int uQ  = w * 16 + l15;                // this lane's unit
  const int HW  = (uQ >> 6) * 1024 + (uQ & 63);// hq write base (+b*64)
  const int BXB = w * 1024 + l15 * 16;         // Bx base (+g*256), bytes

  float c_[4] = {0.f, 0.f, 0.f, 0.f};

  __syncthreads();   // staging visible

  #pragma unroll 1
  for (int t = 0; t < 64; ++t) {
    // opaque zero: one add per base, defeats LICM without per-access cost
    int z = 0;
    asm volatile("" : "+v"(z));
    const int wlb = WLB + z;
    const int hrb = HR + ((t & 1) * 4096) + z;
    const int bxb = BXB + z;
    const int sb  = SB + z;

    // prefetch x for step t+1
    f16 xn = (f16)0.f;
    if (tid < 128) {
      const int tn = (t < 63) ? t + 1 : 63;
      xn = xbuf[(size_t)blockIdx.x * 8192 + tn * 128 + tid];
    }

    // x A-fragment: row=batch=l15, k=lg*8+j valid only for lg==0
    f16x8 ax = {(f16)0.f,(f16)0.f,(f16)0.f,(f16)0.f,
                (f16)0.f,(f16)0.f,(f16)0.f,(f16)0.f};
    if (lg == 0) ax = *(const f16x8*)&x_s[(t & 1) * 128 + l15 * 8];

    i32x4 acc[4];
    #pragma unroll
    for (int g = 0; g < 4; ++g) acc[g] = (i32x4){0, 0, 0, 0};

    // kt2 0,1: B from LDS (lane-contiguous b128)
    #pragma unroll
    for (int kt2 = 0; kt2 < 2; ++kt2) {
      const i32x4 Af = *(const i32x4*)&hq_s[hrb + kt2 * 1024];
      #pragma unroll
      for (int g = 0; g < 4; ++g) {
        const i32x4 Bv = *(const i32x4*)(Wl_s + kt2 * 65536 + g * 1024 + wlb);
        acc[g] = __builtin_amdgcn_mfma_i32_16x16x64_i8(Af, Bv, acc[g], 0, 0, 0);
      }
    }
    // kt2 2,3: B streamed from L2 (coalesced 1024B per (wave,g))
    #pragma unroll
    for (int kt2 = 2; kt2 < 4; ++kt2) {
      const i32x4 Af = *(const i32x4*)&hq_s[hrb + kt2 * 1024];
      #pragma unroll
      for (int g = 0; g < 4; ++g) {
        const i32x4 Bv = *(const i32x4*)(Wq2 + kt2 * 65536 + g * 1024 + sb);
        acc[g] = __builtin_amdgcn_mfma_i32_16x16x64_i8(Af, Bv, acc[g], 0, 0, 0);
      }
    }

    // combine: facc = cvt(acc)*scd + (bias + x@W_ih f16 MFMA)
    f32x4 facc[4];
    #pragma unroll
    for (int g = 0; g < 4; ++g) {
      f32x4 accF = (f32x4){biasv[g], biasv[g], biasv[g], biasv[g]};
      const f16x8 Bv = *(const f16x8*)((const char*)Bx_s + bxb + g * 256);
      accF = __builtin_amdgcn_mfma_f32_16x16x32_f16(ax, Bv, accF, 0, 0, 0);
      #pragma unroll
      for (int e = 0; e < 4; ++e)
        facc[g][e] = (float)acc[g][e] * scv[g] + accF[e];
    }

    // gates + h for unit uQ, batches lg*4+q; fixed scale qs=127
    #pragma unroll
    for (int q = 0; q < 4; ++q) {
      const float gi = facc[0][q];
      const float gf = facc[1][q];
      const float gg = facc[2][q];
      const float go = facc[3][q];
      const float cn = sigm_(gf) * c_[q] + sigm_(gi) * tanh_(gg);
      c_[q] = cn;
      const float h = sigm_(go) * tanh_(cn);
      const int b = lg * 4 + q;
      hq_s[((t + 1) & 1) * 4096 + HW + b * 64] =
          (signed char)(int)rintf(h * 127.f);
      if (t == 63) hnbuf[(size_t)(b0 + b) * H_ + uQ] = h;
    }
    if (tid < 128) x_s[((t + 1) & 1) * 128 + tid] = xn;
    __syncthreads();   // hq/x writes visible; single barrier per step
  }
}

// ---------------------------------------------------------------------------
// Kernel 3: fused MLP head. 512 blocks x 512 threads, 8 batches per block.
// LDS ~41 KB -> 2 blocks/CU = 4 waves/SIMD. unroll-8 k-loops for load ILP.
// ---------------------------------------------------------------------------
__global__ __launch_bounds__(512) void mlp_kernel(
    const float* __restrict__ selfb, const float* __restrict__ hnbuf,
    const float* __restrict__ W1, const float* __restrict__ b1,
    const float* __restrict__ W2, const float* __restrict__ b2,
    const float* __restrict__ Wv, const float* __restrict__ bv,
    float* __restrict__ out) {
  const int tid = threadIdx.x;
  const int b0  = blockIdx.x << 3;      // 8 batches per block
  const int tb  = tid >> 7;             // 0..3 (2 batches each)
  const int tn  = tid & 127;            // float4 column group (N=512)

  __shared__ float a0[8][264];
  __shared__ float a1[8][M1_];
  __shared__ float a2[8][M2_];

  for (int i = tid; i < 8 * SS_; i += 512)
    a0[i / SS_][i % SS_] = selfb[b0 * SS_ + i];
  for (int i = tid; i < 8 * H_; i += 512)
    a0[i >> 8][SS_ + (i & 255)] = hnbuf[((size_t)b0 << 8) + i];
  __syncthreads();

  float4 acc0, acc1;

  { // layer 1: K=261, N=512
    const float4* W14 = (const float4*)W1;
    const float4 bb = ((const float4*)b1)[tn];
    acc0 = bb; acc1 = bb;
    #pragma unroll 8
    for (int k = 0; k < SS_ + H_; ++k) {
      const float4 w0 = W14[k * 128 + tn];
      fma4(acc0, a0[tb * 2 + 0][k], w0);
      fma4(acc1, a0[tb * 2 + 1][k], w0);
    }
    *(float4*)&a1[tb * 2 + 0][tn << 2] = relu4(acc0);
    *(float4*)&a1[tb * 2 + 1][tn << 2] = relu4(acc1);
  }
  __syncthreads();

  { // layer 2: K=512, N=512
    const float4* W24 = (const float4*)W2;
    const float4 bb = ((const float4*)b2)[tn];
    acc0 = bb; acc1 = bb;
    #pragma unroll 8
    for (int k = 0; k < M1_; ++k) {
      const float4 w0 = W24[k * 128 + tn];
      fma4(acc0, a1[tb * 2 + 0][k], w0);
      fma4(acc1, a1[tb * 2 + 1][k], w0);
    }
    *(float4*)&a2[tb * 2 + 0][tn << 2] = relu4(acc0);
    *(float4*)&a2[tb * 2 + 1][tn << 2] = relu4(acc1);
  }
  __syncthreads();

  // layer 3: K=512, N=81
  for (int idx = tid; idx < 8 * A_; idx += 512) {
    const int bi = idx / A_;
    const int n  = idx - bi * A_;
    float sum = bv[n];
    #pragma unroll 8
    for (int k = 0; k < M2_; ++k)
      sum = fmaf(a2[bi][k], Wv[k * A_ + n], sum);
    out[(size_t)(b0 + bi) * A_ + n] = sum;
  }
}

// ---------------------------------------------------------------------------
extern "C" void kernel_launch(void* const* d_in, const int* in_sizes, int n_in,
                              void* d_out, int out_size, void* d_ws, size_t ws_size,
                              hipStream_t stream) {
  const float* state = (const float*)d_in[0];
  const float* W_ih  = (const float*)d_in[1];
  const float* W_hh  = (const float*)d_in[2];
  const float* b_ih  = (const float*)d_in[3];
  const float* b_hh  = (const float*)d_in[4];
  const float* W1    = (const float*)d_in[5];
  const float* b1    = (const float*)d_in[6];
  const float* W2    = (const float*)d_in[7];
  const float* b2    = (const float*)d_in[8];
  const float* Wv    = (const float*)d_in[9];
  const float* bv    = (const float*)d_in[10];
  float* out = (float*)d_out;

  // workspace layout (bytes, 16B-aligned); total ~8.9 MB
  char* ws = (char*)d_ws;
  signed char* Wq2  = (signed char*)(ws);          // 4*1024*64 i8 = 262144 B
  signed char* Wql2 = (signed char*)(ws + 262144); // 2*65536      = 131072 B
  f16*   Wxk     = (f16*)(ws + 393216);            // 1024*8 f16   = 16384 B
  float* bsum_p  = (float*)(ws + 409600);          // 1024 f32     = 4096 B
  float* scd     = (float*)(ws + 413696);          // 1024 f32     = 4096 B
  f16*   xbuf    = (f16*)(ws + 417792);            // 256*64*16*8  = 4194304 B
  float* selfb   = (float*)(ws + 4612096);         // 4096*5 f32   = 81920 B
  float* hnbuf   = (float*)(ws + 4694016);         // 4096*256 f32 = 4194304 B

  pack_weights<<<dim3(64), dim3(1024), 0, stream>>>(W_ih, W_hh, b_ih, b_hh,
                                                    Wq2, Wql2, Wxk, bsum_p, scd);
  sort_gather<<<dim3(B_), dim3(64), 0, stream>>>(state, xbuf, selfb);
  lstm_kernel<<<dim3(B_ / 16), dim3(1024), 156160, stream>>>(xbuf, Wq2, Wql2,
                                                             Wxk, bsum_p, scd,
                                                             hnbuf);
  mlp_kernel<<<dim3(B_ / 8), dim3(512), 0, stream>>>(selfb, hnbuf, W1, b1,
                                                     W2, b2, Wv, bv, out);
}

// Round 17
// 258.298 us; speedup vs baseline: 1.6167x; 1.3804x over previous
//
#include <hip/hip_runtime.h>
#include <math.h>

// Problem constants
#define B_   4096
#define N_   64
#define SS_  5
#define I_   7
#define H_   256
#define M1_  512
#define M2_  512
#define A_   81

typedef _Float16 f16;
typedef f16   f16x8 __attribute__((ext_vector_type(8)));
typedef float f32x4 __attribute__((ext_vector_type(4)));
typedef int   i32x4 __attribute__((ext_vector_type(4)));

__device__ __forceinline__ float sigm_(float x) {
  return __builtin_amdgcn_rcpf(1.f + __expf(-x));
}
__device__ __forceinline__ float tanh_(float x) {
  return 1.f - 2.f * __builtin_amdgcn_rcpf(__expf(2.f * x) + 1.f);
}

// ---------------------------------------------------------------------------
// Kernel 0: pack weights.
// Part A (gtid<65536, one wave per packed col p): LSTM weights as R16:
//   p = w16*64 + g*16 + uu; row = g*256 + w16*16 + uu.
//   Wq2[kt2][p][64] i8 (streamed kt2 2,3); Wql2 lane-contiguous kt2 0,1;
//   scd[p]=mx/127^2; bsum_p; Wxk[p][8] f16.
// Part B: MLP weights -> f16 lane-contiguous B-frag order
//   Wp[( (kt*NT + nt)*16 + l15 )*32 + lg*8 + j] = W[k][n], k=kt*32+lg*8+j,
//   n = nt*16+l15.  W1: Kpad 288, NT 32; W2: K 512, NT 32; Wv: K 512, NT 6
//   (n>=81 zero-padded).
// ---------------------------------------------------------------------------
__global__ __launch_bounds__(1024) void pack_weights(
    const float* __restrict__ W_ih,
    const float* __restrict__ W_hh,
    const float* __restrict__ b_ih,
    const float* __restrict__ b_hh,
    const float* __restrict__ W1,
    const float* __restrict__ W2,
    const float* __restrict__ Wv,
    signed char* __restrict__ Wq2,
    signed char* __restrict__ Wql2,
    f16* __restrict__ Wxk,
    float* __restrict__ bsum_p,
    float* __restrict__ scd,
    f16* __restrict__ Wp1,
    f16* __restrict__ Wp2,
    f16* __restrict__ Wpv) {
  const int gtid = blockIdx.x * 1024 + threadIdx.x;

  if (gtid < 65536) {                   // --- LSTM pack (R16, verified) ---
    const int p    = gtid >> 6;
    const int lane = gtid & 63;
    const int w16 = p >> 6, r = p & 63, g = r >> 4, uu = r & 15;
    const int row = g * H_ + w16 * 16 + uu;

    const float4 v4 = *(const float4*)(W_hh + row * H_ + lane * 4);
    float mx = fmaxf(fmaxf(fabsf(v4.x), fabsf(v4.y)),
                     fmaxf(fabsf(v4.z), fabsf(v4.w)));
    #pragma unroll
    for (int off = 32; off; off >>= 1)
      mx = fmaxf(mx, __shfl_xor(mx, off));
    mx = fmaxf(mx, 1e-12f);
    const float is = 127.f / mx;

    int b0i = (int)rintf(v4.x * is), b1i = (int)rintf(v4.y * is);
    int b2i = (int)rintf(v4.z * is), b3i = (int)rintf(v4.w * is);
    b0i = max(-127, min(127, b0i)); b1i = max(-127, min(127, b1i));
    b2i = max(-127, min(127, b2i)); b3i = max(-127, min(127, b3i));
    const unsigned int packed = (b0i & 0xff) | ((b1i & 0xff) << 8) |
                                ((b2i & 0xff) << 16) | ((b3i & 0xff) << 24);
    const int k    = lane * 4;
    const int kt2  = k >> 6;
    const int kk   = k & 63;
    *(unsigned int*)(Wq2 + kt2 * 65536 + p * 64 + kk) = packed;

    if (kt2 < 2) {
      const int lgk = kk >> 4;
      const int jq  = kk & 15;
      *(unsigned int*)(Wql2 + ((kt2 * 16 + w16) * 4 + g) * 1024 +
                       lgk * 256 + uu * 16 + jq) = packed;
    }

    if (lane < 8)  Wxk[p * 8 + lane] = (lane < I_) ? (f16)W_ih[row * I_ + lane] : (f16)0.f;
    if (lane == 8)  bsum_p[p]  = b_ih[row] + b_hh[row];
    if (lane == 9)  scd[p]     = mx * (1.f / 16129.f);
  }

  // --- MLP packs (independent index spaces) ---
  if (gtid < 288 * 512) {               // W1 (Kpad 288, NT 32)
    const int k = gtid >> 9, n = gtid & 511;
    const int kt = k >> 5, lg = (k >> 3) & 3, j = k & 7;
    const int nt = n >> 4, l15 = n & 15;
    const float v = (k < 261) ? W1[k * 512 + n] : 0.f;
    Wp1[(((kt * 32 + nt) * 16 + l15) * 4 + lg) * 8 + j] = (f16)v;
  }
  if (gtid < 512 * 512) {               // W2 (K 512, NT 32)
    const int k = gtid >> 9, n = gtid & 511;
    const int kt = k >> 5, lg = (k >> 3) & 3, j = k & 7;
    const int nt = n >> 4, l15 = n & 15;
    Wp2[(((kt * 32 + nt) * 16 + l15) * 4 + lg) * 8 + j] = (f16)W2[k * 512 + n];
  }
  if (gtid < 512 * 96) {                // Wv (K 512, NT 6, n pad 96)
    const int k = gtid / 96, n = gtid - k * 96;
    const int kt = k >> 5, lg = (k >> 3) & 3, j = k & 7;
    const int nt = n >> 4, l15 = n & 15;
    const float v = (n < A_) ? Wv[k * A_ + n] : 0.f;
    Wpv[(((kt * 6 + nt) * 16 + l15) * 4 + lg) * 8 + j] = (f16)v;
  }
}

// ---------------------------------------------------------------------------
// Kernel 1: distance + stable descending rank-sort + gather.
// xbuf: f16 [blk][rank(64)][bi(16)][8]; selfbuf: f32 [B][5].
// ---------------------------------------------------------------------------
__global__ void sort_gather(const float* __restrict__ state,
                            f16* __restrict__ xbuf,
                            float* __restrict__ selfbuf) {
  const int b = blockIdx.x;
  const int e = threadIdx.x;                 // 0..63, one wave
  const float* row = state + ((size_t)b * N_ + e) * 12;
  const float4* r4 = (const float4*)row;
  const float4 v0 = r4[0], v1 = r4[1], v2 = r4[2];
  float s[12];
  s[0]=v0.x; s[1]=v0.y; s[2]=v0.z;  s[3]=v0.w;
  s[4]=v1.x; s[5]=v1.y; s[6]=v1.z;  s[7]=v1.w;
  s[8]=v2.x; s[9]=v2.y; s[10]=v2.z; s[11]=v2.w;

  const float s5 = s[5], s6 = s[6];
  const float d = (s5 != 0.f && s6 != 0.f) ? sqrtf(s5 * s5 + s6 * s6) : INFINITY;

  __shared__ float dd[64];
  dd[e] = d;
  __syncthreads();

  int rank = 0;
  #pragma unroll
  for (int j = 0; j < 64; ++j) {
    const float dj = dd[j];
    rank += (dj > d || (dj == d && j < e)) ? 1 : 0;
  }

  f16* xo = xbuf + (((size_t)(b >> 4) * 64 + rank) * 16 + (b & 15)) * 8;
  #pragma unroll
  for (int f = 0; f < I_; ++f) xo[f] = (f16)s[SS_ + f];
  xo[7] = (f16)0.f;

  if (e == 0) {
    #pragma unroll
    for (int i = 0; i < SS_; ++i) selfbuf[b * SS_ + i] = s[i];
  }
}

// ---------------------------------------------------------------------------
// Kernel 2: i8 K=64 MFMA LSTM (UNCHANGED from R16 — passed at 238 us).
// ---------------------------------------------------------------------------
__global__ __attribute__((amdgpu_flat_work_group_size(1024, 1024)))
void lstm_kernel(
    const f16* __restrict__ xbuf,       // [256][64][16][8]
    const signed char* __restrict__ Wq2,// [4][1024][64] i8 (kt2 2,3 used)
    const signed char* __restrict__ Wql2,// [2][16][4][1024] lane-contiguous
    const f16* __restrict__ Wxk,        // [1024][8]
    const float* __restrict__ bsum_p,   // [1024]
    const float* __restrict__ scd,      // [1024]  mx/127^2
    float* __restrict__ hnbuf) {        // [B][256] fp32
  const int tid = threadIdx.x;
  const int l   = tid & 63;
  const int w   = tid >> 6;             // wave 0..15
  const int l15 = l & 15;
  const int lg  = l >> 4;               // 0..3
  const int b0  = blockIdx.x << 4;      // 16 batches per block

  extern __shared__ char smem[];
  signed char* Wl_s = (signed char*)smem;            // 131072 B
  f16*   Bx_s  = (f16*)(smem + 131072);              //  16384 B
  signed char* hq_s = (signed char*)(smem + 147456); //   8192 B [2][4][16][64]
  f16*   x_s   = (f16*)(smem + 155648);              //    512 B [2][16][8]

  {
    const f16x8* sw = (const f16x8*)Wql2;
    f16x8* dw = (f16x8*)Wl_s;
    for (int i = tid; i < 8192; i += 1024) dw[i] = sw[i];
    const f16x8* sx = (const f16x8*)Wxk;
    f16x8* dx = (f16x8*)Bx_s;
    for (int i = tid; i < 1024; i += 1024) dx[i] = sx[i];
    for (int i = tid; i < 2048; i += 1024) ((int*)hq_s)[i] = 0;
    if (tid < 128) x_s[tid] = xbuf[(size_t)blockIdx.x * 8192 + tid]; // t=0 slab
  }

  float biasv[4], scv[4];
  #pragma unroll
  for (int g = 0; g < 4; ++g) {
    const int p = w * 64 + g * 16 + l15;
    biasv[g] = bsum_p[p];
    scv[g]   = scd[p];
  }

  const int WLB = w * 4096 + l * 16;
  const int SB  = w * 4096 + l15 * 64 + lg * 16;
  const int HR  = l15 * 64 + lg * 16;
  const int uQ  = w * 16 + l15;
  const int HW  = (uQ >> 6) * 1024 + (uQ & 63);
  const int BXB = w * 1024 + l15 * 16;

  float c_[4] = {0.f, 0.f, 0.f, 0.f};

  __syncthreads();

  #pragma unroll 1
  for (int t = 0; t < 64; ++t) {
    int z = 0;
    asm volatile("" : "+v"(z));
    const int wlb = WLB + z;
    const int hrb = HR + ((t & 1) * 4096) + z;
    const int bxb = BXB + z;
    const int sb  = SB + z;

    f16 xn = (f16)0.f;
    if (tid < 128) {
      const int tn = (t < 63) ? t + 1 : 63;
      xn = xbuf[(size_t)blockIdx.x * 8192 + tn * 128 + tid];
    }

    f16x8 ax = {(f16)0.f,(f16)0.f,(f16)0.f,(f16)0.f,
                (f16)0.f,(f16)0.f,(f16)0.f,(f16)0.f};
    if (lg == 0) ax = *(const f16x8*)&x_s[(t & 1) * 128 + l15 * 8];

    i32x4 acc[4];
    #pragma unroll
    for (int g = 0; g < 4; ++g) acc[g] = (i32x4){0, 0, 0, 0};

    #pragma unroll
    for (int kt2 = 0; kt2 < 2; ++kt2) {
      const i32x4 Af = *(const i32x4*)&hq_s[hrb + kt2 * 1024];
      #pragma unroll
      for (int g = 0; g < 4; ++g) {
        const i32x4 Bv = *(const i32x4*)(Wl_s + kt2 * 65536 + g * 1024 + wlb);
        acc[g] = __builtin_amdgcn_mfma_i32_16x16x64_i8(Af, Bv, acc[g], 0, 0, 0);
      }
    }
    #pragma unroll
    for (int kt2 = 2; kt2 < 4; ++kt2) {
      const i32x4 Af = *(const i32x4*)&hq_s[hrb + kt2 * 1024];
      #pragma unroll
      for (int g = 0; g < 4; ++g) {
        const i32x4 Bv = *(const i32x4*)(Wq2 + kt2 * 65536 + g * 1024 + sb);
        acc[g] = __builtin_amdgcn_mfma_i32_16x16x64_i8(Af, Bv, acc[g], 0, 0, 0);
      }
    }

    f32x4 facc[4];
    #pragma unroll
    for (int g = 0; g < 4; ++g) {
      f32x4 accF = (f32x4){biasv[g], biasv[g], biasv[g], biasv[g]};
      const f16x8 Bv = *(const f16x8*)((const char*)Bx_s + bxb + g * 256);
      accF = __builtin_amdgcn_mfma_f32_16x16x32_f16(ax, Bv, accF, 0, 0, 0);
      #pragma unroll
      for (int e = 0; e < 4; ++e)
        facc[g][e] = (float)acc[g][e] * scv[g] + accF[e];
    }

    #pragma unroll
    for (int q = 0; q < 4; ++q) {
      const float gi = facc[0][q];
      const float gf = facc[1][q];
      const float gg = facc[2][q];
      const float go = facc[3][q];
      const float cn = sigm_(gf) * c_[q] + sigm_(gi) * tanh_(gg);
      c_[q] = cn;
      const float h = sigm_(go) * tanh_(cn);
      const int b = lg * 4 + q;
      hq_s[((t + 1) & 1) * 4096 + HW + b * 64] =
          (signed char)(int)rintf(h * 127.f);
      if (t == 63) hnbuf[(size_t)(b0 + b) * H_ + uQ] = h;
    }
    if (tid < 128) x_s[((t + 1) & 1) * 128 + tid] = xn;
    __syncthreads();
  }
}

// ---------------------------------------------------------------------------
// Kernel 3: MFMA MLP. 128 blocks x 512 threads (8 waves), 32 batches/block.
// f16 activations through LDS (padded strides), f16 weights streamed from
// L2 in lane-contiguous B-frag order (1024B coalesced per (nt,kt) read).
// Fragment conventions identical to lstm (verified): A row=l15 k=lg*8+j;
// B col=l15; D col=l15 row=lg*4+e. Biases f32, accum f32.
// LDS: aA 32x296 f16 18944 + aB 32x520 33280 + aC 32x520 33280 = 85504 B.
// ---------------------------------------------------------------------------
__global__ __launch_bounds__(512) void mlp_kernel(
    const float* __restrict__ selfb, const float* __restrict__ hnbuf,
    const f16* __restrict__ Wp1, const float* __restrict__ b1,
    const f16* __restrict__ Wp2, const float* __restrict__ b2,
    const f16* __restrict__ Wpv, const float* __restrict__ bv,
    float* __restrict__ out) {
  const int tid = threadIdx.x;
  const int l   = tid & 63;
  const int w   = tid >> 6;             // wave 0..7
  const int l15 = l & 15;
  const int lg  = l >> 4;
  const int b0  = blockIdx.x << 5;      // 32 batches per block

  extern __shared__ char smem[];
  f16* aA = (f16*)smem;                         // [32][296]
  f16* aB = (f16*)(smem + 18944);               // [32][520]
  f16* aC = (f16*)(smem + 18944 + 33280);       // [32][520]

  // stage joint = [self(5) | hn(256) | zeros..287] as f16, stride 296
  for (int i = tid; i < 32 * 296; i += 512) {
    const int r = i / 296, cc = i - r * 296;
    float v = 0.f;
    if (cc < SS_)        v = selfb[(b0 + r) * SS_ + cc];
    else if (cc < 261)   v = hnbuf[((size_t)(b0 + r)) * H_ + cc - SS_];
    aA[i] = (f16)v;
  }
  __syncthreads();

  f32x4 acc[2][4];

  { // ---- layer 1: Kpad=288 (9 kt), N=512; wave owns nt = w*4+nt4
    #pragma unroll
    for (int mt = 0; mt < 2; ++mt)
      #pragma unroll
      for (int nt4 = 0; nt4 < 4; ++nt4) acc[mt][nt4] = (f32x4){0.f,0.f,0.f,0.f};
    for (int kt = 0; kt < 9; ++kt) {
      const f16x8 A0 = *(const f16x8*)&aA[(l15) * 296 + kt * 32 + lg * 8];
      const f16x8 A1 = *(const f16x8*)&aA[(16 + l15) * 296 + kt * 32 + lg * 8];
      #pragma unroll
      for (int nt4 = 0; nt4 < 4; ++nt4) {
        const int nt = w * 4 + nt4;
        const f16x8 Bv = *(const f16x8*)(Wp1 + (((kt * 32 + nt) * 16 + l15) * 4 + lg) * 8);
        acc[0][nt4] = __builtin_amdgcn_mfma_f32_16x16x32_f16(A0, Bv, acc[0][nt4], 0, 0, 0);
        acc[1][nt4] = __builtin_amdgcn_mfma_f32_16x16x32_f16(A1, Bv, acc[1][nt4], 0, 0, 0);
      }
    }
    #pragma unroll
    for (int nt4 = 0; nt4 < 4; ++nt4) {
      const int n = (w * 4 + nt4) * 16 + l15;
      const float bb = b1[n];
      #pragma unroll
      for (int mt = 0; mt < 2; ++mt)
        #pragma unroll
        for (int e = 0; e < 4; ++e) {
          const float v = fmaxf(acc[mt][nt4][e] + bb, 0.f);
          aB[(mt * 16 + lg * 4 + e) * 520 + n] = (f16)v;
        }
    }
  }
  __syncthreads();

  { // ---- layer 2: K=512 (16 kt), N=512
    #pragma unroll
    for (int mt = 0; mt < 2; ++mt)
      #pragma unroll
      for (int nt4 = 0; nt4 < 4; ++nt4) acc[mt][nt4] = (f32x4){0.f,0.f,0.f,0.f};
    for (int kt = 0; kt < 16; ++kt) {
      const f16x8 A0 = *(const f16x8*)&aB[(l15) * 520 + kt * 32 + lg * 8];
      const f16x8 A1 = *(const f16x8*)&aB[(16 + l15) * 520 + kt * 32 + lg * 8];
      #pragma unroll
      for (int nt4 = 0; nt4 < 4; ++nt4) {
        const int nt = w * 4 + nt4;
        const f16x8 Bv = *(const f16x8*)(Wp2 + (((kt * 32 + nt) * 16 + l15) * 4 + lg) * 8);
        acc[0][nt4] = __builtin_amdgcn_mfma_f32_16x16x32_f16(A0, Bv, acc[0][nt4], 0, 0, 0);
        acc[1][nt4] = __builtin_amdgcn_mfma_f32_16x16x32_f16(A1, Bv, acc[1][nt4], 0, 0, 0);
      }
    }
    #pragma unroll
    for (int nt4 = 0; nt4 < 4; ++nt4) {
      const int n = (w * 4 + nt4) * 16 + l15;
      const float bb = b2[n];
      #pragma unroll
      for (int mt = 0; mt < 2; ++mt)
        #pragma unroll
        for (int e = 0; e < 4; ++e) {
          const float v = fmaxf(acc[mt][nt4][e] + bb, 0.f);
          aC[(mt * 16 + lg * 4 + e) * 520 + n] = (f16)v;
        }
    }
  }
  __syncthreads();

  // ---- layer 3: K=512 (16 kt), N=81 pad 96 (6 tiles); waves 0..5
  if (w < 6) {
    const int n = w * 16 + l15;
    f32x4 acc3[2];
    acc3[0] = (f32x4){0.f,0.f,0.f,0.f};
    acc3[1] = (f32x4){0.f,0.f,0.f,0.f};
    for (int kt = 0; kt < 16; ++kt) {
      const f16x8 A0 = *(const f16x8*)&aC[(l15) * 520 + kt * 32 + lg * 8];
      const f16x8 A1 = *(const f16x8*)&aC[(16 + l15) * 520 + kt * 32 + lg * 8];
      const f16x8 Bv = *(const f16x8*)(Wpv + (((kt * 6 + w) * 16 + l15) * 4 + lg) * 8);
      acc3[0] = __builtin_amdgcn_mfma_f32_16x16x32_f16(A0, Bv, acc3[0], 0, 0, 0);
      acc3[1] = __builtin_amdgcn_mfma_f32_16x16x32_f16(A1, Bv, acc3[1], 0, 0, 0);
    }
    if (n < A_) {
      const float bb = bv[n];
      #pragma unroll
      for (int mt = 0; mt < 2; ++mt)
        #pragma unroll
        for (int e = 0; e < 4; ++e)
          out[(size_t)(b0 + mt * 16 + lg * 4 + e) * A_ + n] = acc3[mt][e] + bb;
    }
  }
}

// ---------------------------------------------------------------------------
extern "C" void kernel_launch(void* const* d_in, const int* in_sizes, int n_in,
                              void* d_out, int out_size, void* d_ws, size_t ws_size,
                              hipStream_t stream) {
  const float* state = (const float*)d_in[0];
  const float* W_ih  = (const float*)d_in[1];
  const float* W_hh  = (const float*)d_in[2];
  const float* b_ih  = (const float*)d_in[3];
  const float* b_hh  = (const float*)d_in[4];
  const float* W1    = (const float*)d_in[5];
  const float* b1    = (const float*)d_in[6];
  const float* W2    = (const float*)d_in[7];
  const float* b2    = (const float*)d_in[8];
  const float* Wv    = (const float*)d_in[9];
  const float* bv    = (const float*)d_in[10];
  float* out = (float*)d_out;

  // workspace layout (bytes, 16B-aligned); total ~9.8 MB
  char* ws = (char*)d_ws;
  signed char* Wq2  = (signed char*)(ws);          // 262144 B
  signed char* Wql2 = (signed char*)(ws + 262144); // 131072 B
  f16*   Wxk     = (f16*)(ws + 393216);            // 16384 B
  float* bsum_p  = (float*)(ws + 409600);          // 4096 B
  float* scd     = (float*)(ws + 413696);          // 4096 B
  f16*   xbuf    = (f16*)(ws + 417792);            // 4194304 B
  float* selfb   = (float*)(ws + 4612096);         // 81920 B
  float* hnbuf   = (float*)(ws + 4694016);         // 4194304 B
  f16*   Wp1     = (f16*)(ws + 8888320);           // 288*512*2 = 294912 B
  f16*   Wp2     = (f16*)(ws + 9183232);           // 512*512*2 = 524288 B
  f16*   Wpv     = (f16*)(ws + 9707520);           // 512*96*2  = 98304 B

  pack_weights<<<dim3(256), dim3(1024), 0, stream>>>(
      W_ih, W_hh, b_ih, b_hh, W1, W2, Wv,
      Wq2, Wql2, Wxk, bsum_p, scd, Wp1, Wp2, Wpv);
  sort_gather<<<dim3(B_), dim3(64), 0, stream>>>(state, xbuf, selfb);
  lstm_kernel<<<dim3(B_ / 16), dim3(1024), 156160, stream>>>(xbuf, Wq2, Wql2,
                                                             Wxk, bsum_p, scd,
                                                             hnbuf);
  mlp_kernel<<<dim3(B_ / 32), dim3(512), 85504, stream>>>(selfb, hnbuf,
                                                          Wp1, b1, Wp2, b2,
                                                          Wpv, bv, out);
}

// Round 18
// 232.986 us; speedup vs baseline: 1.7923x; 1.1086x over previous
//
#include <hip/hip_runtime.h>
#include <math.h>

// Problem constants
#define B_   4096
#define N_   64
#define SS_  5
#define I_   7
#define H_   256
#define M1_  512
#define M2_  512
#define A_   81

typedef _Float16 f16;
typedef f16   f16x8 __attribute__((ext_vector_type(8)));
typedef float f32x4 __attribute__((ext_vector_type(4)));
typedef int   i32x4 __attribute__((ext_vector_type(4)));

__device__ __forceinline__ float sigm_(float x) {
  return __builtin_amdgcn_rcpf(1.f + __expf(-x));
}
__device__ __forceinline__ float tanh_(float x) {
  return 1.f - 2.f * __builtin_amdgcn_rcpf(__expf(2.f * x) + 1.f);
}

// ---------------------------------------------------------------------------
// Kernel 0: pack weights (UNCHANGED from R17 — same layouts serve the
// swapped-operand MFMA since A/B fragments share the lane mapping).
// ---------------------------------------------------------------------------
__global__ __launch_bounds__(1024) void pack_weights(
    const float* __restrict__ W_ih,
    const float* __restrict__ W_hh,
    const float* __restrict__ b_ih,
    const float* __restrict__ b_hh,
    const float* __restrict__ W1,
    const float* __restrict__ W2,
    const float* __restrict__ Wv,
    signed char* __restrict__ Wq2,
    signed char* __restrict__ Wql2,
    f16* __restrict__ Wxk,
    float* __restrict__ bsum_p,
    float* __restrict__ scd,
    f16* __restrict__ Wp1,
    f16* __restrict__ Wp2,
    f16* __restrict__ Wpv) {
  const int gtid = blockIdx.x * 1024 + threadIdx.x;

  if (gtid < 65536) {                   // --- LSTM pack ---
    const int p    = gtid >> 6;
    const int lane = gtid & 63;
    const int w16 = p >> 6, r = p & 63, g = r >> 4, uu = r & 15;
    const int row = g * H_ + w16 * 16 + uu;

    const float4 v4 = *(const float4*)(W_hh + row * H_ + lane * 4);
    float mx = fmaxf(fmaxf(fabsf(v4.x), fabsf(v4.y)),
                     fmaxf(fabsf(v4.z), fabsf(v4.w)));
    #pragma unroll
    for (int off = 32; off; off >>= 1)
      mx = fmaxf(mx, __shfl_xor(mx, off));
    mx = fmaxf(mx, 1e-12f);
    const float is = 127.f / mx;

    int b0i = (int)rintf(v4.x * is), b1i = (int)rintf(v4.y * is);
    int b2i = (int)rintf(v4.z * is), b3i = (int)rintf(v4.w * is);
    b0i = max(-127, min(127, b0i)); b1i = max(-127, min(127, b1i));
    b2i = max(-127, min(127, b2i)); b3i = max(-127, min(127, b3i));
    const unsigned int packed = (b0i & 0xff) | ((b1i & 0xff) << 8) |
                                ((b2i & 0xff) << 16) | ((b3i & 0xff) << 24);
    const int k    = lane * 4;
    const int kt2  = k >> 6;
    const int kk   = k & 63;
    *(unsigned int*)(Wq2 + kt2 * 65536 + p * 64 + kk) = packed;

    if (kt2 < 2) {
      const int lgk = kk >> 4;
      const int jq  = kk & 15;
      *(unsigned int*)(Wql2 + ((kt2 * 16 + w16) * 4 + g) * 1024 +
                       lgk * 256 + uu * 16 + jq) = packed;
    }

    if (lane < 8)  Wxk[p * 8 + lane] = (lane < I_) ? (f16)W_ih[row * I_ + lane] : (f16)0.f;
    if (lane == 8)  bsum_p[p]  = b_ih[row] + b_hh[row];
    if (lane == 9)  scd[p]     = mx * (1.f / 16129.f);
  }

  // --- MLP packs ---
  if (gtid < 288 * 512) {               // W1 (Kpad 288, NT 32)
    const int k = gtid >> 9, n = gtid & 511;
    const int kt = k >> 5, lg = (k >> 3) & 3, j = k & 7;
    const int nt = n >> 4, l15 = n & 15;
    const float v = (k < 261) ? W1[k * 512 + n] : 0.f;
    Wp1[(((kt * 32 + nt) * 16 + l15) * 4 + lg) * 8 + j] = (f16)v;
  }
  if (gtid < 512 * 512) {               // W2 (K 512, NT 32)
    const int k = gtid >> 9, n = gtid & 511;
    const int kt = k >> 5, lg = (k >> 3) & 3, j = k & 7;
    const int nt = n >> 4, l15 = n & 15;
    Wp2[(((kt * 32 + nt) * 16 + l15) * 4 + lg) * 8 + j] = (f16)W2[k * 512 + n];
  }
  if (gtid < 512 * 96) {                // Wv (K 512, NT 6, n pad 96)
    const int k = gtid / 96, n = gtid - k * 96;
    const int kt = k >> 5, lg = (k >> 3) & 3, j = k & 7;
    const int nt = n >> 4, l15 = n & 15;
    const float v = (n < A_) ? Wv[k * A_ + n] : 0.f;
    Wpv[(((kt * 6 + nt) * 16 + l15) * 4 + lg) * 8 + j] = (f16)v;
  }
}

// ---------------------------------------------------------------------------
// Kernel 1: distance + stable descending rank-sort + gather (unchanged).
// ---------------------------------------------------------------------------
__global__ void sort_gather(const float* __restrict__ state,
                            f16* __restrict__ xbuf,
                            float* __restrict__ selfbuf) {
  const int b = blockIdx.x;
  const int e = threadIdx.x;                 // 0..63, one wave
  const float* row = state + ((size_t)b * N_ + e) * 12;
  const float4* r4 = (const float4*)row;
  const float4 v0 = r4[0], v1 = r4[1], v2 = r4[2];
  float s[12];
  s[0]=v0.x; s[1]=v0.y; s[2]=v0.z;  s[3]=v0.w;
  s[4]=v1.x; s[5]=v1.y; s[6]=v1.z;  s[7]=v1.w;
  s[8]=v2.x; s[9]=v2.y; s[10]=v2.z; s[11]=v2.w;

  const float s5 = s[5], s6 = s[6];
  const float d = (s5 != 0.f && s6 != 0.f) ? sqrtf(s5 * s5 + s6 * s6) : INFINITY;

  __shared__ float dd[64];
  dd[e] = d;
  __syncthreads();

  int rank = 0;
  #pragma unroll
  for (int j = 0; j < 64; ++j) {
    const float dj = dd[j];
    rank += (dj > d || (dj == d && j < e)) ? 1 : 0;
  }

  f16* xo = xbuf + (((size_t)(b >> 4) * 64 + rank) * 16 + (b & 15)) * 8;
  #pragma unroll
  for (int f = 0; f < I_; ++f) xo[f] = (f16)s[SS_ + f];
  xo[7] = (f16)0.f;

  if (e == 0) {
    #pragma unroll
    for (int i = 0; i < SS_; ++i) selfbuf[b * SS_ + i] = s[i];
  }
}

// ---------------------------------------------------------------------------
// Kernel 2: i8 K=64 MFMA LSTM, SWAPPED operands. 256 blocks x 1024 threads
// (16 waves, 4/SIMD), 16 batches/block. acc[g] = mfma(A=W, B=hq): D =
// [row=unit][col=batch] -> lane owns 4 CONSECUTIVE units (w*16+lg*4+e) x
// 1 batch (l15). hq publish = one packed dword/lane into an 80B-stride
// batch layout: write banks 2-way (free), read balanced, 16B-aligned.
// hn write = single coalesced float4. Weight buffers/addresses unchanged
// (A/B fragments share the lane mapping).
// LDS: Wl 131072 + Bx 16384 + hq 2x5120 + x 512 = 158208 B.
// ---------------------------------------------------------------------------
__global__ __attribute__((amdgpu_flat_work_group_size(1024, 1024)))
void lstm_kernel(
    const f16* __restrict__ xbuf,       // [256][64][16][8]
    const signed char* __restrict__ Wq2,// [4][1024][64] i8 (kt2 2,3 used)
    const signed char* __restrict__ Wql2,// [2][16][4][1024] lane-contiguous
    const f16* __restrict__ Wxk,        // [1024][8]
    const float* __restrict__ bsum_p,   // [1024]
    const float* __restrict__ scd,      // [1024]  mx/127^2
    float* __restrict__ hnbuf) {        // [B][256] fp32
  const int tid = threadIdx.x;
  const int l   = tid & 63;
  const int w   = tid >> 6;             // wave 0..15
  const int l15 = l & 15;
  const int lg  = l >> 4;               // 0..3
  const int b0  = blockIdx.x << 4;      // 16 batches per block

  extern __shared__ char smem[];
  signed char* Wl_s = (signed char*)smem;            // 131072 B
  f16*   Bx_s  = (f16*)(smem + 131072);              //  16384 B
  signed char* hq_s = (signed char*)(smem + 147456); //  10240 B [2][4][16][80]
  f16*   x_s   = (f16*)(smem + 157696);              //    512 B [2][16][8]

  {
    const f16x8* sw = (const f16x8*)Wql2;
    f16x8* dw = (f16x8*)Wl_s;
    for (int i = tid; i < 8192; i += 1024) dw[i] = sw[i];
    const f16x8* sx = (const f16x8*)Wxk;
    f16x8* dx = (f16x8*)Bx_s;
    for (int i = tid; i < 1024; i += 1024) dx[i] = sx[i];
    for (int i = tid; i < 2560; i += 1024) ((int*)hq_s)[i] = 0;
    if (tid < 128) x_s[tid] = xbuf[(size_t)blockIdx.x * 8192 + tid]; // t=0 slab
  }

  // per-lane constants: gates g of units u = w*16 + lg*4 + e, batch l15
  float biasv[4][4], scv[4][4];
  #pragma unroll
  for (int g = 0; g < 4; ++g)
    #pragma unroll
    for (int e = 0; e < 4; ++e) {
      const int p = w * 64 + g * 16 + lg * 4 + e;
      biasv[g][e] = bsum_p[p];
      scv[g][e]   = scd[p];
    }

  const int WLB = w * 4096 + l * 16;              // LDS W (A-frag) base
  const int SB  = w * 4096 + l15 * 64 + lg * 16;  // streamed W (A-frag) base
  const int HR  = l15 * 80 + lg * 16;             // hq B-frag base (+kt2*1280)
  const int HW  = (w >> 2) * 1280 + l15 * 80 + (w & 3) * 16 + lg * 4; // write
  const int BXB = w * 1024 + l15 * 16;            // Wx A-frag base (+g*256)
  const int u0  = w * 16 + lg * 4;                // first of 4 owned units

  float c_[4] = {0.f, 0.f, 0.f, 0.f};

  __syncthreads();

  #pragma unroll 1
  for (int t = 0; t < 64; ++t) {
    int z = 0;
    asm volatile("" : "+v"(z));
    const int wlb = WLB + z;
    const int hrb = HR + ((t & 1) * 5120) + z;
    const int bxb = BXB + z;
    const int sb  = SB + z;

    f16 xn = (f16)0.f;
    if (tid < 128) {
      const int tn = (t < 63) ? t + 1 : 63;
      xn = xbuf[(size_t)blockIdx.x * 8192 + tn * 128 + tid];
    }

    // x B-fragment: col=batch=l15, k=lg*8+j valid only for lg==0
    f16x8 bx = {(f16)0.f,(f16)0.f,(f16)0.f,(f16)0.f,
                (f16)0.f,(f16)0.f,(f16)0.f,(f16)0.f};
    if (lg == 0) bx = *(const f16x8*)&x_s[(t & 1) * 128 + l15 * 8];

    i32x4 acc[4];
    #pragma unroll
    for (int g = 0; g < 4; ++g) acc[g] = (i32x4){0, 0, 0, 0};

    // kt2 0,1: W (A) from LDS; hq (B) from LDS
    #pragma unroll
    for (int kt2 = 0; kt2 < 2; ++kt2) {
      const i32x4 Hf = *(const i32x4*)&hq_s[hrb + kt2 * 1280];
      #pragma unroll
      for (int g = 0; g < 4; ++g) {
        const i32x4 Wv = *(const i32x4*)(Wl_s + kt2 * 65536 + g * 1024 + wlb);
        acc[g] = __builtin_amdgcn_mfma_i32_16x16x64_i8(Wv, Hf, acc[g], 0, 0, 0);
      }
    }
    // kt2 2,3: W (A) streamed from L2
    #pragma unroll
    for (int kt2 = 2; kt2 < 4; ++kt2) {
      const i32x4 Hf = *(const i32x4*)&hq_s[hrb + kt2 * 1280];
      #pragma unroll
      for (int g = 0; g < 4; ++g) {
        const i32x4 Wv = *(const i32x4*)(Wq2 + kt2 * 65536 + g * 1024 + sb);
        acc[g] = __builtin_amdgcn_mfma_i32_16x16x64_i8(Wv, Hf, acc[g], 0, 0, 0);
      }
    }

    // combine: facc = cvt(acc)*scd + (bias + x@W_ih f16 MFMA, swapped)
    f32x4 facc[4];
    #pragma unroll
    for (int g = 0; g < 4; ++g) {
      f32x4 accF = (f32x4){biasv[g][0], biasv[g][1], biasv[g][2], biasv[g][3]};
      const f16x8 Wxv = *(const f16x8*)((const char*)Bx_s + bxb + g * 256);
      accF = __builtin_amdgcn_mfma_f32_16x16x32_f16(Wxv, bx, accF, 0, 0, 0);
      #pragma unroll
      for (int e = 0; e < 4; ++e)
        facc[g][e] = (float)acc[g][e] * scv[g][e] + accF[e];
    }

    // gates + h for units u0..u0+3, batch l15; pack one dword
    float hv[4];
    #pragma unroll
    for (int e = 0; e < 4; ++e) {
      const float gi = facc[0][e];
      const float gf = facc[1][e];
      const float gg = facc[2][e];
      const float go = facc[3][e];
      const float cn = sigm_(gf) * c_[e] + sigm_(gi) * tanh_(gg);
      c_[e] = cn;
      hv[e] = sigm_(go) * tanh_(cn);
    }
    const int q0 = (int)rintf(hv[0] * 127.f) & 255;
    const int q1 = (int)rintf(hv[1] * 127.f) & 255;
    const int q2 = (int)rintf(hv[2] * 127.f) & 255;
    const int q3 = (int)rintf(hv[3] * 127.f) & 255;
    *(unsigned int*)(hq_s + ((t + 1) & 1) * 5120 + HW) =
        (unsigned int)(q0 | (q1 << 8) | (q2 << 16) | (q3 << 24));
    if (t == 63) {
      float4 hx = {hv[0], hv[1], hv[2], hv[3]};
      *(float4*)&hnbuf[(size_t)(b0 + l15) * H_ + u0] = hx;
    }
    if (tid < 128) x_s[((t + 1) & 1) * 128 + tid] = xn;
    __syncthreads();
  }
}

// ---------------------------------------------------------------------------
// Kernel 3: MFMA MLP (unchanged from R17 — passed, ~12 us).
// ---------------------------------------------------------------------------
__global__ __launch_bounds__(512) void mlp_kernel(
    const float* __restrict__ selfb, const float* __restrict__ hnbuf,
    const f16* __restrict__ Wp1, const float* __restrict__ b1,
    const f16* __restrict__ Wp2, const float* __restrict__ b2,
    const f16* __restrict__ Wpv, const float* __restrict__ bv,
    float* __restrict__ out) {
  const int tid = threadIdx.x;
  const int l   = tid & 63;
  const int w   = tid >> 6;             // wave 0..7
  const int l15 = l & 15;
  const int lg  = l >> 4;
  const int b0  = blockIdx.x << 5;      // 32 batches per block

  extern __shared__ char smem[];
  f16* aA = (f16*)smem;                         // [32][296]
  f16* aB = (f16*)(smem + 18944);               // [32][520]
  f16* aC = (f16*)(smem + 18944 + 33280);       // [32][520]

  for (int i = tid; i < 32 * 296; i += 512) {
    const int r = i / 296, cc = i - r * 296;
    float v = 0.f;
    if (cc < SS_)        v = selfb[(b0 + r) * SS_ + cc];
    else if (cc < 261)   v = hnbuf[((size_t)(b0 + r)) * H_ + cc - SS_];
    aA[i] = (f16)v;
  }
  __syncthreads();

  f32x4 acc[2][4];

  { // ---- layer 1: Kpad=288 (9 kt), N=512
    #pragma unroll
    for (int mt = 0; mt < 2; ++mt)
      #pragma unroll
      for (int nt4 = 0; nt4 < 4; ++nt4) acc[mt][nt4] = (f32x4){0.f,0.f,0.f,0.f};
    for (int kt = 0; kt < 9; ++kt) {
      const f16x8 A0 = *(const f16x8*)&aA[(l15) * 296 + kt * 32 + lg * 8];
      const f16x8 A1 = *(const f16x8*)&aA[(16 + l15) * 296 + kt * 32 + lg * 8];
      #pragma unroll
      for (int nt4 = 0; nt4 < 4; ++nt4) {
        const int nt = w * 4 + nt4;
        const f16x8 Bv = *(const f16x8*)(Wp1 + (((kt * 32 + nt) * 16 + l15) * 4 + lg) * 8);
        acc[0][nt4] = __builtin_amdgcn_mfma_f32_16x16x32_f16(A0, Bv, acc[0][nt4], 0, 0, 0);
        acc[1][nt4] = __builtin_amdgcn_mfma_f32_16x16x32_f16(A1, Bv, acc[1][nt4], 0, 0, 0);
      }
    }
    #pragma unroll
    for (int nt4 = 0; nt4 < 4; ++nt4) {
      const int n = (w * 4 + nt4) * 16 + l15;
      const float bb = b1[n];
      #pragma unroll
      for (int mt = 0; mt < 2; ++mt)
        #pragma unroll
        for (int e = 0; e < 4; ++e) {
          const float v = fmaxf(acc[mt][nt4][e] + bb, 0.f);
          aB[(mt * 16 + lg * 4 + e) * 520 + n] = (f16)v;
        }
    }
  }
  __syncthreads();

  { // ---- layer 2: K=512 (16 kt), N=512
    #pragma unroll
    for (int mt = 0; mt < 2; ++mt)
      #pragma unroll
      for (int nt4 = 0; nt4 < 4; ++nt4) acc[mt][nt4] = (f32x4){0.f,0.f,0.f,0.f};
    for (int kt = 0; kt < 16; ++kt) {
      const f16x8 A0 = *(const f16x8*)&aB[(l15) * 520 + kt * 32 + lg * 8];
      const f16x8 A1 = *(const f16x8*)&aB[(16 + l15) * 520 + kt * 32 + lg * 8];
      #pragma unroll
      for (int nt4 = 0; nt4 < 4; ++nt4) {
        const int nt = w * 4 + nt4;
        const f16x8 Bv = *(const f16x8*)(Wp2 + (((kt * 32 + nt) * 16 + l15) * 4 + lg) * 8);
        acc[0][nt4] = __builtin_amdgcn_mfma_f32_16x16x32_f16(A0, Bv, acc[0][nt4], 0, 0, 0);
        acc[1][nt4] = __builtin_amdgcn_mfma_f32_16x16x32_f16(A1, Bv, acc[1][nt4], 0, 0, 0);
      }
    }
    #pragma unroll
    for (int nt4 = 0; nt4 < 4; ++nt4) {
      const int n = (w * 4 + nt4) * 16 + l15;
      const float bb = b2[n];
      #pragma unroll
      for (int mt = 0; mt < 2; ++mt)
        #pragma unroll
        for (int e = 0; e < 4; ++e) {
          const float v = fmaxf(acc[mt][nt4][e] + bb, 0.f);
          aC[(mt * 16 + lg * 4 + e) * 520 + n] = (f16)v;
        }
    }
  }
  __syncthreads();

  // ---- layer 3: K=512 (16 kt), N=81 pad 96 (6 tiles); waves 0..5
  if (w < 6) {
    const int n = w * 16 + l15;
    f32x4 acc3[2];
    acc3[0] = (f32x4){0.f,0.f,0.f,0.f};
    acc3[1] = (f32x4){0.f,0.f,0.f,0.f};
    for (int kt = 0; kt < 16; ++kt) {
      const f16x8 A0 = *(const f16x8*)&aC[(l15) * 520 + kt * 32 + lg * 8];
      const f16x8 A1 = *(const f16x8*)&aC[(16 + l15) * 520 + kt * 32 + lg * 8];
      const f16x8 Bv = *(const f16x8*)(Wpv + (((kt * 6 + w) * 16 + l15) * 4 + lg) * 8);
      acc3[0] = __builtin_amdgcn_mfma_f32_16x16x32_f16(A0, Bv, acc3[0], 0, 0, 0);
      acc3[1] = __builtin_amdgcn_mfma_f32_16x16x32_f16(A1, Bv, acc3[1], 0, 0, 0);
    }
    if (n < A_) {
      const float bb = bv[n];
      #pragma unroll
      for (int mt = 0; mt < 2; ++mt)
        #pragma unroll
        for (int e = 0; e < 4; ++e)
          out[(size_t)(b0 + mt * 16 + lg * 4 + e) * A_ + n] = acc3[mt][e] + bb;
    }
  }
}

// ---------------------------------------------------------------------------
extern "C" void kernel_launch(void* const* d_in, const int* in_sizes, int n_in,
                              void* d_out, int out_size, void* d_ws, size_t ws_size,
                              hipStream_t stream) {
  const float* state = (const float*)d_in[0];
  const float* W_ih  = (const float*)d_in[1];
  const float* W_hh  = (const float*)d_in[2];
  const float* b_ih  = (const float*)d_in[3];
  const float* b_hh  = (const float*)d_in[4];
  const float* W1    = (const float*)d_in[5];
  const float* b1    = (const float*)d_in[6];
  const float* W2    = (const float*)d_in[7];
  const float* b2    = (const float*)d_in[8];
  const float* Wv    = (const float*)d_in[9];
  const float* bv    = (const float*)d_in[10];
  float* out = (float*)d_out;

  // workspace layout (bytes, 16B-aligned); total ~9.8 MB
  char* ws = (char*)d_ws;
  signed char* Wq2  = (signed char*)(ws);          // 262144 B
  signed char* Wql2 = (signed char*)(ws + 262144); // 131072 B
  f16*   Wxk     = (f16*)(ws + 393216);            // 16384 B
  float* bsum_p  = (float*)(ws + 409600);          // 4096 B
  float* scd     = (float*)(ws + 413696);          // 4096 B
  f16*   xbuf    = (f16*)(ws + 417792);            // 4194304 B
  float* selfb   = (float*)(ws + 4612096);         // 81920 B
  float* hnbuf   = (float*)(ws + 4694016);         // 4194304 B
  f16*   Wp1     = (f16*)(ws + 8888320);           // 294912 B
  f16*   Wp2     = (f16*)(ws + 9183232);           // 524288 B
  f16*   Wpv     = (f16*)(ws + 9707520);           // 98304 B

  pack_weights<<<dim3(256), dim3(1024), 0, stream>>>(
      W_ih, W_hh, b_ih, b_hh, W1, W2, Wv,
      Wq2, Wql2, Wxk, bsum_p, scd, Wp1, Wp2, Wpv);
  sort_gather<<<dim3(B_), dim3(64), 0, stream>>>(state, xbuf, selfb);
  lstm_kernel<<<dim3(B_ / 16), dim3(1024), 158208, stream>>>(xbuf, Wq2, Wql2,
                                                             Wxk, bsum_p, scd,
                                                             hnbuf);
  mlp_kernel<<<dim3(B_ / 32), dim3(512), 85504, stream>>>(selfb, hnbuf,
                                                          Wp1, b1, Wp2, b2,
                                                          Wpv, bv, out);
}

// Round 19
// 172.350 us; speedup vs baseline: 2.4229x; 1.3518x over previous
//
#include <hip/hip_runtime.h>
#include <math.h>

// Problem constants
#define B_   4096
#define N_   64
#define SS_  5
#define I_   7
#define H_   256
#define M1_  512
#define M2_  512
#define A_   81

typedef _Float16 f16;
typedef f16   f16x8 __attribute__((ext_vector_type(8)));
typedef float f32x4 __attribute__((ext_vector_type(4)));
typedef int   i32x4 __attribute__((ext_vector_type(4)));

__device__ __forceinline__ float sigm_(float x) {
  return __builtin_amdgcn_rcpf(1.f + __expf(-x));
}
__device__ __forceinline__ float tanh_(float x) {
  return 1.f - 2.f * __builtin_amdgcn_rcpf(__expf(2.f * x) + 1.f);
}

// ---------------------------------------------------------------------------
// Kernel 0: pack weights. LSTM part as R16/R18; bias now folded into the
// x-weight slot j=7 (consumed by x[7]=1.0), so Wxk[p][7] = b_ih+b_hh.
// MLP packs unchanged (R17).
// ---------------------------------------------------------------------------
__global__ __launch_bounds__(1024) void pack_weights(
    const float* __restrict__ W_ih,
    const float* __restrict__ W_hh,
    const float* __restrict__ b_ih,
    const float* __restrict__ b_hh,
    const float* __restrict__ W1,
    const float* __restrict__ W2,
    const float* __restrict__ Wv,
    signed char* __restrict__ Wq2,
    signed char* __restrict__ Wql2,
    f16* __restrict__ Wxk,
    float* __restrict__ scd,
    f16* __restrict__ Wp1,
    f16* __restrict__ Wp2,
    f16* __restrict__ Wpv) {
  const int gtid = blockIdx.x * 1024 + threadIdx.x;

  if (gtid < 65536) {                   // --- LSTM pack ---
    const int p    = gtid >> 6;
    const int lane = gtid & 63;
    const int w16 = p >> 6, r = p & 63, g = r >> 4, uu = r & 15;
    const int row = g * H_ + w16 * 16 + uu;

    const float4 v4 = *(const float4*)(W_hh + row * H_ + lane * 4);
    float mx = fmaxf(fmaxf(fabsf(v4.x), fabsf(v4.y)),
                     fmaxf(fabsf(v4.z), fabsf(v4.w)));
    #pragma unroll
    for (int off = 32; off; off >>= 1)
      mx = fmaxf(mx, __shfl_xor(mx, off));
    mx = fmaxf(mx, 1e-12f);
    const float is = 127.f / mx;

    int b0i = (int)rintf(v4.x * is), b1i = (int)rintf(v4.y * is);
    int b2i = (int)rintf(v4.z * is), b3i = (int)rintf(v4.w * is);
    b0i = max(-127, min(127, b0i)); b1i = max(-127, min(127, b1i));
    b2i = max(-127, min(127, b2i)); b3i = max(-127, min(127, b3i));
    const unsigned int packed = (b0i & 0xff) | ((b1i & 0xff) << 8) |
                                ((b2i & 0xff) << 16) | ((b3i & 0xff) << 24);
    const int k    = lane * 4;
    const int kt2  = k >> 6;
    const int kk   = k & 63;
    *(unsigned int*)(Wq2 + kt2 * 65536 + p * 64 + kk) = packed;

    if (kt2 < 2) {
      const int lgk = kk >> 4;
      const int jq  = kk & 15;
      *(unsigned int*)(Wql2 + ((kt2 * 16 + w16) * 4 + g) * 1024 +
                       lgk * 256 + uu * 16 + jq) = packed;
    }

    if (lane < 8) {
      f16 v;
      if (lane < I_)      v = (f16)W_ih[row * I_ + lane];
      else                v = (f16)(b_ih[row] + b_hh[row]);   // bias in j=7
      Wxk[p * 8 + lane] = v;
    }
    if (lane == 9)  scd[p] = mx * (1.f / 16129.f);
  }

  // --- MLP packs ---
  if (gtid < 288 * 512) {               // W1 (Kpad 288, NT 32)
    const int k = gtid >> 9, n = gtid & 511;
    const int kt = k >> 5, lg = (k >> 3) & 3, j = k & 7;
    const int nt = n >> 4, l15 = n & 15;
    const float v = (k < 261) ? W1[k * 512 + n] : 0.f;
    Wp1[(((kt * 32 + nt) * 16 + l15) * 4 + lg) * 8 + j] = (f16)v;
  }
  if (gtid < 512 * 512) {               // W2 (K 512, NT 32)
    const int k = gtid >> 9, n = gtid & 511;
    const int kt = k >> 5, lg = (k >> 3) & 3, j = k & 7;
    const int nt = n >> 4, l15 = n & 15;
    Wp2[(((kt * 32 + nt) * 16 + l15) * 4 + lg) * 8 + j] = (f16)W2[k * 512 + n];
  }
  if (gtid < 512 * 96) {                // Wv (K 512, NT 6, n pad 96)
    const int k = gtid / 96, n = gtid - k * 96;
    const int kt = k >> 5, lg = (k >> 3) & 3, j = k & 7;
    const int nt = n >> 4, l15 = n & 15;
    const float v = (n < A_) ? Wv[k * A_ + n] : 0.f;
    Wpv[(((kt * 6 + nt) * 16 + l15) * 4 + lg) * 8 + j] = (f16)v;
  }
}

// ---------------------------------------------------------------------------
// Kernel 1: distance + stable descending rank-sort + gather.
// x slot 7 now carries the constant 1.0 (bias-fold input).
// ---------------------------------------------------------------------------
__global__ void sort_gather(const float* __restrict__ state,
                            f16* __restrict__ xbuf,
                            float* __restrict__ selfbuf) {
  const int b = blockIdx.x;
  const int e = threadIdx.x;                 // 0..63, one wave
  const float* row = state + ((size_t)b * N_ + e) * 12;
  const float4* r4 = (const float4*)row;
  const float4 v0 = r4[0], v1 = r4[1], v2 = r4[2];
  float s[12];
  s[0]=v0.x; s[1]=v0.y; s[2]=v0.z;  s[3]=v0.w;
  s[4]=v1.x; s[5]=v1.y; s[6]=v1.z;  s[7]=v1.w;
  s[8]=v2.x; s[9]=v2.y; s[10]=v2.z; s[11]=v2.w;

  const float s5 = s[5], s6 = s[6];
  const float d = (s5 != 0.f && s6 != 0.f) ? sqrtf(s5 * s5 + s6 * s6) : INFINITY;

  __shared__ float dd[64];
  dd[e] = d;
  __syncthreads();

  int rank = 0;
  #pragma unroll
  for (int j = 0; j < 64; ++j) {
    const float dj = dd[j];
    rank += (dj > d || (dj == d && j < e)) ? 1 : 0;
  }

  f16* xo = xbuf + (((size_t)(b >> 4) * 64 + rank) * 16 + (b & 15)) * 8;
  #pragma unroll
  for (int f = 0; f < I_; ++f) xo[f] = (f16)s[SS_ + f];
  xo[7] = (f16)1.f;                     // bias-fold slot

  if (e == 0) {
    #pragma unroll
    for (int i = 0; i < SS_; ++i) selfbuf[b * SS_ + i] = s[i];
  }
}

// ---------------------------------------------------------------------------
// Kernel 2: i8 K=64 MFMA LSTM, swapped operands + register-resident
// streamed weights + conflict-free hq. 256 blocks x 1024 threads (16 waves,
// 4/SIMD), 16 batches/block.
// - kt2 0,1 W from LDS (lane-contiguous); kt2 2,3 W held in 32 REGISTERS
//   loop-invariantly (demand ~90 <= the 128-reg tier -> no sinking).
// - hq layout [2buf][kg=unit/16][batch][16B]: read = kt2*1024 + l*16
//   (contiguous, 0-conflict), write = w*256+l15*16+lg*4 (2-way, free).
// - bias folded into x-MFMA (x[7]=1, Wx[p][7]=bias).
// LDS: Wl 131072 + Bx 16384 + hq 8192 + x 512 = 156160 B.
// ---------------------------------------------------------------------------
__global__ __attribute__((amdgpu_flat_work_group_size(1024, 1024)))
void lstm_kernel(
    const f16* __restrict__ xbuf,       // [256][64][16][8]
    const signed char* __restrict__ Wq2,// [4][1024][64] i8 (kt2 2,3 used)
    const signed char* __restrict__ Wql2,// [2][16][4][1024] lane-contiguous
    const f16* __restrict__ Wxk,        // [1024][8] (j=7 is bias)
    const float* __restrict__ scd,      // [1024]  mx/127^2
    float* __restrict__ hnbuf) {        // [B][256] fp32
  const int tid = threadIdx.x;
  const int l   = tid & 63;
  const int w   = tid >> 6;             // wave 0..15
  const int l15 = l & 15;
  const int lg  = l >> 4;               // 0..3
  const int b0  = blockIdx.x << 4;      // 16 batches per block

  extern __shared__ char smem[];
  signed char* Wl_s = (signed char*)smem;            // 131072 B
  f16*   Bx_s  = (f16*)(smem + 131072);              //  16384 B
  signed char* hq_s = (signed char*)(smem + 147456); //   8192 B [2][16][16][16]
  f16*   x_s   = (f16*)(smem + 155648);              //    512 B [2][16][8]

  {
    const f16x8* sw = (const f16x8*)Wql2;
    f16x8* dw = (f16x8*)Wl_s;
    for (int i = tid; i < 8192; i += 1024) dw[i] = sw[i];
    const f16x8* sx = (const f16x8*)Wxk;
    f16x8* dx = (f16x8*)Bx_s;
    for (int i = tid; i < 1024; i += 1024) dx[i] = sx[i];
    for (int i = tid; i < 2048; i += 1024) ((int*)hq_s)[i] = 0;
    if (tid < 128) x_s[tid] = xbuf[(size_t)blockIdx.x * 8192 + tid]; // t=0 slab
  }

  // per-lane dequant scales: gates g of units u = w*16 + lg*4 + e
  float scv[4][4];
  #pragma unroll
  for (int g = 0; g < 4; ++g)
    #pragma unroll
    for (int e = 0; e < 4; ++e)
      scv[g][e] = scd[w * 64 + g * 16 + lg * 4 + e];

  const int WLB = w * 4096 + l * 16;              // LDS W (A-frag) base
  const int SB  = w * 4096 + l15 * 64 + lg * 16;  // streamed W (A-frag) base
  const int BXB = w * 1024 + l15 * 16;            // Wx A-frag base (+g*256)
  const int u0  = w * 16 + lg * 4;                // first of 4 owned units
  const int HW  = w * 256 + l15 * 16 + lg * 4;    // hq write (+buf*4096)
  const int HR  = l * 16;                         // hq read  (+buf*4096+kt2*1024)

  // streamed W (kt2 2,3) -> REGISTERS, loop-invariant (32 VGPRs; fits tier)
  i32x4 Bs[2][4];
  #pragma unroll
  for (int m = 0; m < 2; ++m)
    #pragma unroll
    for (int g = 0; g < 4; ++g)
      Bs[m][g] = *(const i32x4*)(Wq2 + (2 + m) * 65536 + g * 1024 + SB);

  float c_[4] = {0.f, 0.f, 0.f, 0.f};

  __syncthreads();

  #pragma unroll 1
  for (int t = 0; t < 64; ++t) {
    int z = 0;
    asm volatile("" : "+v"(z));          // launders only LDS-read bases
    const int wlb = WLB + z;
    const int hrb = HR + ((t & 1) * 4096) + z;
    const int bxb = BXB + z;

    f16 xn = (f16)0.f;
    if (tid < 128) {
      const int tn = (t < 63) ? t + 1 : 63;
      xn = xbuf[(size_t)blockIdx.x * 8192 + tn * 128 + tid];
    }

    // x B-fragment: col=batch=l15, k=lg*8+j valid only for lg==0
    f16x8 bx = {(f16)0.f,(f16)0.f,(f16)0.f,(f16)0.f,
                (f16)0.f,(f16)0.f,(f16)0.f,(f16)0.f};
    if (lg == 0) bx = *(const f16x8*)&x_s[(t & 1) * 128 + l15 * 8];

    i32x4 acc[4];
    #pragma unroll
    for (int g = 0; g < 4; ++g) acc[g] = (i32x4){0, 0, 0, 0};

    // kt2 0,1: W (A) from LDS; hq (B) from LDS (both conflict-free)
    #pragma unroll
    for (int kt2 = 0; kt2 < 2; ++kt2) {
      const i32x4 Hf = *(const i32x4*)&hq_s[hrb + kt2 * 1024];
      #pragma unroll
      for (int g = 0; g < 4; ++g) {
        const i32x4 Wv = *(const i32x4*)(Wl_s + kt2 * 65536 + g * 1024 + wlb);
        acc[g] = __builtin_amdgcn_mfma_i32_16x16x64_i8(Wv, Hf, acc[g], 0, 0, 0);
      }
    }
    // kt2 2,3: W (A) from registers
    #pragma unroll
    for (int m = 0; m < 2; ++m) {
      const i32x4 Hf = *(const i32x4*)&hq_s[hrb + (2 + m) * 1024];
      #pragma unroll
      for (int g = 0; g < 4; ++g)
        acc[g] = __builtin_amdgcn_mfma_i32_16x16x64_i8(Bs[m][g], Hf, acc[g], 0, 0, 0);
    }

    // combine: facc = cvt(acc)*scd + (x@W_ih + bias, via swapped f16 MFMA)
    f32x4 facc[4];
    #pragma unroll
    for (int g = 0; g < 4; ++g) {
      f32x4 accF = (f32x4){0.f, 0.f, 0.f, 0.f};
      const f16x8 Wxv = *(const f16x8*)((const char*)Bx_s + bxb + g * 256);
      accF = __builtin_amdgcn_mfma_f32_16x16x32_f16(Wxv, bx, accF, 0, 0, 0);
      #pragma unroll
      for (int e = 0; e < 4; ++e)
        facc[g][e] = (float)acc[g][e] * scv[g][e] + accF[e];
    }

    // gates + h for units u0..u0+3, batch l15; pack one dword
    float hv[4];
    #pragma unroll
    for (int e = 0; e < 4; ++e) {
      const float gi = facc[0][e];
      const float gf = facc[1][e];
      const float gg = facc[2][e];
      const float go = facc[3][e];
      const float cn = sigm_(gf) * c_[e] + sigm_(gi) * tanh_(gg);
      c_[e] = cn;
      hv[e] = sigm_(go) * tanh_(cn);
    }
    const int q0 = (int)rintf(hv[0] * 127.f) & 255;
    const int q1 = (int)rintf(hv[1] * 127.f) & 255;
    const int q2 = (int)rintf(hv[2] * 127.f) & 255;
    const int q3 = (int)rintf(hv[3] * 127.f) & 255;
    *(unsigned int*)(hq_s + ((t + 1) & 1) * 4096 + HW) =
        (unsigned int)(q0 | (q1 << 8) | (q2 << 16) | (q3 << 24));
    if (t == 63) {
      float4 hx = {hv[0], hv[1], hv[2], hv[3]};
      *(float4*)&hnbuf[(size_t)(b0 + l15) * H_ + u0] = hx;
    }
    if (tid < 128) x_s[((t + 1) & 1) * 128 + tid] = xn;
    __syncthreads();
  }
}

// ---------------------------------------------------------------------------
// Kernel 3: MFMA MLP (unchanged from R17 — ~12 us).
// ---------------------------------------------------------------------------
__global__ __launch_bounds__(512) void mlp_kernel(
    const float* __restrict__ selfb, const float* __restrict__ hnbuf,
    const f16* __restrict__ Wp1, const float* __restrict__ b1,
    const f16* __restrict__ Wp2, const float* __restrict__ b2,
    const f16* __restrict__ Wpv, const float* __restrict__ bv,
    float* __restrict__ out) {
  const int tid = threadIdx.x;
  const int l   = tid & 63;
  const int w   = tid >> 6;             // wave 0..7
  const int l15 = l & 15;
  const int lg  = l >> 4;
  const int b0  = blockIdx.x << 5;      // 32 batches per block

  extern __shared__ char smem[];
  f16* aA = (f16*)smem;                         // [32][296]
  f16* aB = (f16*)(smem + 18944);               // [32][520]
  f16* aC = (f16*)(smem + 18944 + 33280);       // [32][520]

  for (int i = tid; i < 32 * 296; i += 512) {
    const int r = i / 296, cc = i - r * 296;
    float v = 0.f;
    if (cc < SS_)        v = selfb[(b0 + r) * SS_ + cc];
    else if (cc < 261)   v = hnbuf[((size_t)(b0 + r)) * H_ + cc - SS_];
    aA[i] = (f16)v;
  }
  __syncthreads();

  f32x4 acc[2][4];

  { // ---- layer 1: Kpad=288 (9 kt), N=512
    #pragma unroll
    for (int mt = 0; mt < 2; ++mt)
      #pragma unroll
      for (int nt4 = 0; nt4 < 4; ++nt4) acc[mt][nt4] = (f32x4){0.f,0.f,0.f,0.f};
    for (int kt = 0; kt < 9; ++kt) {
      const f16x8 A0 = *(const f16x8*)&aA[(l15) * 296 + kt * 32 + lg * 8];
      const f16x8 A1 = *(const f16x8*)&aA[(16 + l15) * 296 + kt * 32 + lg * 8];
      #pragma unroll
      for (int nt4 = 0; nt4 < 4; ++nt4) {
        const int nt = w * 4 + nt4;
        const f16x8 Bv = *(const f16x8*)(Wp1 + (((kt * 32 + nt) * 16 + l15) * 4 + lg) * 8);
        acc[0][nt4] = __builtin_amdgcn_mfma_f32_16x16x32_f16(A0, Bv, acc[0][nt4], 0, 0, 0);
        acc[1][nt4] = __builtin_amdgcn_mfma_f32_16x16x32_f16(A1, Bv, acc[1][nt4], 0, 0, 0);
      }
    }
    #pragma unroll
    for (int nt4 = 0; nt4 < 4; ++nt4) {
      const int n = (w * 4 + nt4) * 16 + l15;
      const float bb = b1[n];
      #pragma unroll
      for (int mt = 0; mt < 2; ++mt)
        #pragma unroll
        for (int e = 0; e < 4; ++e) {
          const float v = fmaxf(acc[mt][nt4][e] + bb, 0.f);
          aB[(mt * 16 + lg * 4 + e) * 520 + n] = (f16)v;
        }
    }
  }
  __syncthreads();

  { // ---- layer 2: K=512 (16 kt), N=512
    #pragma unroll
    for (int mt = 0; mt < 2; ++mt)
      #pragma unroll
      for (int nt4 = 0; nt4 < 4; ++nt4) acc[mt][nt4] = (f32x4){0.f,0.f,0.f,0.f};
    for (int kt = 0; kt < 16; ++kt) {
      const f16x8 A0 = *(const f16x8*)&aB[(l15) * 520 + kt * 32 + lg * 8];
      const f16x8 A1 = *(const f16x8*)&aB[(16 + l15) * 520 + kt * 32 + lg * 8];
      #pragma unroll
      for (int nt4 = 0; nt4 < 4; ++nt4) {
        const int nt = w * 4 + nt4;
        const f16x8 Bv = *(const f16x8*)(Wp2 + (((kt * 32 + nt) * 16 + l15) * 4 + lg) * 8);
        acc[0][nt4] = __builtin_amdgcn_mfma_f32_16x16x32_f16(A0, Bv, acc[0][nt4], 0, 0, 0);
        acc[1][nt4] = __builtin_amdgcn_mfma_f32_16x16x32_f16(A1, Bv, acc[1][nt4], 0, 0, 0);
      }
    }
    #pragma unroll
    for (int nt4 = 0; nt4 < 4; ++nt4) {
      const int n = (w * 4 + nt4) * 16 + l15;
      const float bb = b2[n];
      #pragma unroll
      for (int mt = 0; mt < 2; ++mt)
        #pragma unroll
        for (int e = 0; e < 4; ++e) {
          const float v = fmaxf(acc[mt][nt4][e] + bb, 0.f);
          aC[(mt * 16 + lg * 4 + e) * 520 + n] = (f16)v;
        }
    }
  }
  __syncthreads();

  // ---- layer 3: K=512 (16 kt), N=81 pad 96 (6 tiles); waves 0..5
  if (w < 6) {
    const int n = w * 16 + l15;
    f32x4 acc3[2];
    acc3[0] = (f32x4){0.f,0.f,0.f,0.f};
    acc3[1] = (f32x4){0.f,0.f,0.f,0.f};
    for (int kt = 0; kt < 16; ++kt) {
      const f16x8 A0 = *(const f16x8*)&aC[(l15) * 520 + kt * 32 + lg * 8];
      const f16x8 A1 = *(const f16x8*)&aC[(16 + l15) * 520 + kt * 32 + lg * 8];
      const f16x8 Bv = *(const f16x8*)(Wpv + (((kt * 6 + w) * 16 + l15) * 4 + lg) * 8);
      acc3[0] = __builtin_amdgcn_mfma_f32_16x16x32_f16(A0, Bv, acc3[0], 0, 0, 0);
      acc3[1] = __builtin_amdgcn_mfma_f32_16x16x32_f16(A1, Bv, acc3[1], 0, 0, 0);
    }
    if (n < A_) {
      const float bb = bv[n];
      #pragma unroll
      for (int mt = 0; mt < 2; ++mt)
        #pragma unroll
        for (int e = 0; e < 4; ++e)
          out[(size_t)(b0 + mt * 16 + lg * 4 + e) * A_ + n] = acc3[mt][e] + bb;
    }
  }
}

// ---------------------------------------------------------------------------
extern "C" void kernel_launch(void* const* d_in, const int* in_sizes, int n_in,
                              void* d_out, int out_size, void* d_ws, size_t ws_size,
                              hipStream_t stream) {
  const float* state = (const float*)d_in[0];
  const float* W_ih  = (const float*)d_in[1];
  const float* W_hh  = (const float*)d_in[2];
  const float* b_ih  = (const float*)d_in[3];
  const float* b_hh  = (const float*)d_in[4];
  const float* W1    = (const float*)d_in[5];
  const float* b1    = (const float*)d_in[6];
  const float* W2    = (const float*)d_in[7];
  const float* b2    = (const float*)d_in[8];
  const float* Wv    = (const float*)d_in[9];
  const float* bv    = (const float*)d_in[10];
  float* out = (float*)d_out;

  // workspace layout (bytes, 16B-aligned); total ~9.8 MB
  char* ws = (char*)d_ws;
  signed char* Wq2  = (signed char*)(ws);          // 262144 B
  signed char* Wql2 = (signed char*)(ws + 262144); // 131072 B
  f16*   Wxk     = (f16*)(ws + 393216);            // 16384 B
  float* scd     = (float*)(ws + 413696);          // 4096 B
  f16*   xbuf    = (f16*)(ws + 417792);            // 4194304 B
  float* selfb   = (float*)(ws + 4612096);         // 81920 B
  float* hnbuf   = (float*)(ws + 4694016);         // 4194304 B
  f16*   Wp1     = (f16*)(ws + 8888320);           // 294912 B
  f16*   Wp2     = (f16*)(ws + 9183232);           // 524288 B
  f16*   Wpv     = (f16*)(ws + 9707520);           // 98304 B

  pack_weights<<<dim3(256), dim3(1024), 0, stream>>>(
      W_ih, W_hh, b_ih, b_hh, W1, W2, Wv,
      Wq2, Wql2, Wxk, scd, Wp1, Wp2, Wpv);
  sort_gather<<<dim3(B_), dim3(64), 0, stream>>>(state, xbuf, selfb);
  lstm_kernel<<<dim3(B_ / 16), dim3(1024), 156160, stream>>>(xbuf, Wq2, Wql2,
                                                             Wxk, scd, hnbuf);
  mlp_kernel<<<dim3(B_ / 32), dim3(512), 85504, stream>>>(selfb, hnbuf,
                                                          Wp1, b1, Wp2, b2,
                                                          Wpv, bv, out);
}